// Round 1
// 1082.204 us; speedup vs baseline: 1.0417x; 1.0417x over previous
//
#include <hip/hip_runtime.h>
#include <math.h>

#define BB 64
#define DD 128
#define NN 400
#define MM 50
#define HH 8
#define KDIM 16
#define NC 4
#define KW 7

#define SZ_C (BB * DD * NN)   // 3,276,800
#define SZ_Q (BB * DD * MM)   //   409,600
#define SSTAT (BB * NN + BB * MM)  // 28,800; q stats at offset BB*NN

// ---------------- canonical weight transpose: Wcan[m][d][e] ----------------
// m 0..3: pw_w (e-major), m 4: Wo (d-major, copy), m 5: Wfc (e-major),
// m 6..8: Wq/Wk/Wv ([h][d][kd], e = h*16+kd)
__global__ void k_transposeW(const float* __restrict__ pw_w, const float* __restrict__ Wo,
                             const float* __restrict__ Wfc, const float* __restrict__ Wq,
                             const float* __restrict__ Wk, const float* __restrict__ Wv,
                             float* __restrict__ Wcan) {
  int idx = blockIdx.x * 256 + threadIdx.x;
  if (idx >= 9 * 16384) return;
  int m = idx >> 14;
  int r = idx & 16383;
  int d = r >> 7, e = r & 127;
  float v;
  if (m < 4) v = pw_w[m * 16384 + e * 128 + d];
  else if (m == 4) v = Wo[d * 128 + e];
  else if (m == 5) v = Wfc[e * 128 + d];
  else {
    const float* W = (m == 6) ? Wq : (m == 7) ? Wk : Wv;
    v = W[((e >> 4) * 128 + d) * 16 + (e & 15)];
  }
  Wcan[idx] = v;
}

// ---------------- position encoding add (both phases) ----------------
__global__ void k_pe(const float* __restrict__ xC, const float* __restrict__ xQ,
                     float* __restrict__ yC, float* __restrict__ yQ) {
  int idx = blockIdx.x * 256 + threadIdx.x;
  const float* x; float* y; int L, id2;
  if (idx < SZ_C) { x = xC; y = yC; L = NN; id2 = idx; }
  else if (idx < SZ_C + SZ_Q) { x = xQ; y = yQ; L = MM; id2 = idx - SZ_C; }
  else return;
  int l = id2 % L;
  int d = (id2 / L) % DD;
  int de = d & ~1;
  float freq = __expf((float)de * (-9.210340371976184f / 128.0f));
  float phase = (d & 1) ? 1.5707963267948966f : 0.0f;
  y[id2] = x[id2] + sinf((float)l * freq + phase);
}

// ---------------- LN stats: mu and 1/(sd+eps), ddof=1 ----------------
// blocks 0..447: ctx (b=blk/7, lt=blk%7); 448..511: q (b=blk-448)
__global__ void k_lnstats(const float* __restrict__ xC, const float* __restrict__ xQ,
                          float* __restrict__ mu, float* __restrict__ inv) {
  int blk = blockIdx.x;
  const float* x; int L, lt, b, soff;
  if (blk < 448) { b = blk / 7; lt = blk % 7; x = xC; L = NN; soff = 0; }
  else { b = blk - 448; lt = 0; x = xQ; L = MM; soff = BB * NN; }
  int ll = threadIdx.x & 63;
  int dq = threadIdx.x >> 6;
  int l = lt * 64 + ll;
  __shared__ float s_sum[4][64], s_sq[4][64];
  float sum = 0.f, sq = 0.f;
  const float* px = x + (size_t)b * DD * L + l;
  if (l < L) {
    for (int d = dq * 32; d < dq * 32 + 32; ++d) {
      float v = px[(size_t)d * L];
      sum += v; sq += v * v;
    }
  }
  s_sum[dq][ll] = sum; s_sq[dq][ll] = sq;
  __syncthreads();
  if (dq == 0 && l < L) {
    float ts = s_sum[0][ll] + s_sum[1][ll] + s_sum[2][ll] + s_sum[3][ll];
    float tq = s_sq[0][ll] + s_sq[1][ll] + s_sq[2][ll] + s_sq[3][ll];
    float m = ts * (1.0f / 128.0f);
    float var = (tq - 128.0f * m * m) * (1.0f / 127.0f);
    float sd = sqrtf(fmaxf(var, 0.f));
    mu[soff + b * L + l] = m;
    inv[soff + b * L + l] = 1.0f / (sd + 1e-6f);
  }
}

// ---------------- depthwise conv K=7 pad=3, LN fused (both phases) ----------------
__global__ void k_dw(const float* __restrict__ xC, const float* __restrict__ xQ,
                     float* __restrict__ yC, float* __restrict__ yQ,
                     const float* __restrict__ w, const float* __restrict__ bias,
                     const float* __restrict__ mu, const float* __restrict__ inv,
                     const float* __restrict__ g, const float* __restrict__ beta) {
  int idx = blockIdx.x * 256 + threadIdx.x;
  const float* x; float* y; int L, id2, soff;
  if (idx < SZ_C) { x = xC; y = yC; L = NN; id2 = idx; soff = 0; }
  else if (idx < SZ_C + SZ_Q) { x = xQ; y = yQ; L = MM; id2 = idx - SZ_C; soff = BB * NN; }
  else return;
  int l = id2 % L;
  int d = (id2 / L) % DD;
  int b = id2 / (DD * L);
  const float* px = x + (size_t)(id2 - l);
  const float* pmu = mu + soff + b * L;
  const float* pin = inv + soff + b * L;
  float gd = g[d], bd = beta[d];
  float acc = bias[d];
  #pragma unroll
  for (int k = 0; k < KW; ++k) {
    int lt = l + k - 3;
    if (lt >= 0 && lt < L) {
      float v = gd * (px[lt] - pmu[lt]) * pin[lt] + bd;
      acc += v * w[d * KW + k];
    }
  }
  y[id2] = acc;
}

// ---------------- 128x128 GEMM over [B,128,L], both phases ----------------
// out[b,e,l] (+)= act(sum_d xln[b,d,l] * Wc[d][e] + bias[e])
// LNF: apply LN with stats during X staging. ACT: 0=write, 1=+residual, 2=relu+residual
template <int LNF, int ACT>
__global__ __launch_bounds__(256) void k_gemm128(
    const float* __restrict__ xC, const float* __restrict__ xQ,
    float* __restrict__ outC, float* __restrict__ outQ,
    const float* __restrict__ Wc, const float* __restrict__ bias,
    const float* __restrict__ mu, const float* __restrict__ inv,
    const float* __restrict__ g, const float* __restrict__ beta) {
  int blk = blockIdx.x;
  int b = blk / 5, tile = blk % 5;
  const float* x; float* out; int L, l0, soff;
  if (tile < 4) { x = xC; out = outC; L = NN; l0 = tile * 128; soff = 0; }
  else { x = xQ; out = outQ; L = MM; l0 = 0; soff = BB * NN; }
  __shared__ float Wl[32 * 128];
  __shared__ float Xl[32 * 128];
  int tid = threadIdx.x;
  float acc[8][8];
  #pragma unroll
  for (int i = 0; i < 8; ++i)
    #pragma unroll
    for (int j = 0; j < 8; ++j) acc[i][j] = 0.f;
  const float* xb = x + (size_t)b * DD * L;
  const float* pmu = mu + soff + b * L;
  const float* pin = inv + soff + b * L;
  for (int kc = 0; kc < 4; ++kc) {
    int d0 = kc * 32;
    #pragma unroll
    for (int i = 0; i < 16; ++i) {
      int idx = i * 256 + tid;
      Wl[idx] = Wc[(size_t)(d0 + (idx >> 7)) * 128 + (idx & 127)];
    }
    #pragma unroll
    for (int i = 0; i < 16; ++i) {
      int idx = i * 256 + tid;
      int k = idx >> 7, l = idx & 127;
      float v = 0.f;
      if (l0 + l < L) {
        v = xb[(size_t)(d0 + k) * L + l0 + l];
        if (LNF) v = g[d0 + k] * (v - pmu[l0 + l]) * pin[l0 + l] + beta[d0 + k];
      }
      Xl[idx] = v;
    }
    __syncthreads();
    int e0 = (tid >> 4) * 8, lq = (tid & 15) * 8;
    for (int k = 0; k < 32; ++k) {
      const float4* wp = (const float4*)&Wl[k * 128 + e0];
      const float4* xp = (const float4*)&Xl[k * 128 + lq];
      float4 w0 = wp[0], w1 = wp[1], x0 = xp[0], x1 = xp[1];
      float we[8] = {w0.x, w0.y, w0.z, w0.w, w1.x, w1.y, w1.z, w1.w};
      float xe[8] = {x0.x, x0.y, x0.z, x0.w, x1.x, x1.y, x1.z, x1.w};
      #pragma unroll
      for (int i = 0; i < 8; ++i)
        #pragma unroll
        for (int j = 0; j < 8; ++j) acc[i][j] += we[i] * xe[j];
    }
    __syncthreads();
  }
  int e0 = (tid >> 4) * 8, lq = l0 + (tid & 15) * 8;
  #pragma unroll
  for (int i = 0; i < 8; ++i) {
    float bi = bias[e0 + i];
    float* po = out + ((size_t)b * DD + e0 + i) * L;
    #pragma unroll
    for (int j = 0; j < 8; ++j) {
      int l = lq + j;
      if (l < L) {
        float v = acc[i][j] + bi;
        if (ACT == 2) v = fmaxf(v, 0.f);
        if (ACT == 0) po[l] = v;
        else po[l] = v + po[l];
      }
    }
  }
}

// ---------------- attention: block per (b,h,phase); K,V,maskadd in LDS ----------------
// q/k/v/o are [B,128,L] planes, channel = h*16+t. Each thread owns TWO queries
// (i, i+256) so every broadcast K/V LDS read is amortized over 2 dot/accum chains
// (2x ILP, half the LDS-issue + address math per useful FMA).
__global__ __launch_bounds__(256) void k_attn2(
    const float* __restrict__ qC, const float* __restrict__ kC, const float* __restrict__ vC,
    const float* __restrict__ qQ, const float* __restrict__ kQ, const float* __restrict__ vQ,
    const float* __restrict__ cmask, const float* __restrict__ qmask,
    float* __restrict__ oC, float* __restrict__ oQ) {
  int blk = blockIdx.x;
  const float *qp, *kp, *vp, *mk; float* op; int L, b, h;
  if (blk < 512) { b = blk >> 3; h = blk & 7; qp = qC; kp = kC; vp = vC; mk = cmask; op = oC; L = NN; }
  else { int bb = blk - 512; b = bb >> 3; h = bb & 7; qp = qQ; kp = kQ; vp = vQ; mk = qmask; op = oQ; L = MM; }
  __shared__ float Kl[NN * KDIM];
  __shared__ float Vl[NN * KDIM];
  __shared__ float Ml[NN];  // staged additive mask: -1e30*(1-m), -1e30 in pad rows
  int tid = threadIdx.x;
  size_t base = ((size_t)b * DD + h * KDIM) * L;
  int KP = (L + 7) & ~7;  // keys padded to multiple of 8 (400 -> 400, 50 -> 56)
  for (int idx = tid; idx < KDIM * L; idx += 256) {
    int t = idx / L, j = idx - t * L;
    Kl[j * KDIM + t] = kp[base + (size_t)t * L + j];
    Vl[j * KDIM + t] = vp[base + (size_t)t * L + j];
  }
  for (int idx = tid; idx < (KP - L) * KDIM; idx += 256) {
    int j = L + (idx >> 4), t = idx & 15;
    Kl[j * KDIM + t] = 0.f; Vl[j * KDIM + t] = 0.f;
  }
  for (int j = tid; j < KP; j += 256)
    Ml[j] = (j < L) ? -1e30f * (1.0f - mk[b * L + j]) : -1e30f;
  __syncthreads();
  // query phase: only 50 queries; waves 1-3 are done after staging
  if (L == MM && tid >= 64) return;

  int i1 = tid, i2 = tid + 256;
  bool a1 = i1 < L, a2 = i2 < L;
  float q1[KDIM], q2[KDIM];
  #pragma unroll
  for (int t = 0; t < KDIM; ++t) {
    q1[t] = a1 ? qp[base + (size_t)t * L + i1] * 0.25f : 0.f;  // 1/sqrt(16) folded in
    q2[t] = a2 ? qp[base + (size_t)t * L + i2] * 0.25f : 0.f;
  }
  float m1 = -1e30f, m2 = -1e30f, ls1 = 0.f, ls2 = 0.f;
  float acc1[KDIM], acc2[KDIM];
  #pragma unroll
  for (int t = 0; t < KDIM; ++t) { acc1[t] = 0.f; acc2[t] = 0.f; }
  for (int j0 = 0; j0 < KP; j0 += 8) {
    const float4* mp = (const float4*)&Ml[j0];
    float4 ma0 = mp[0], ma1 = mp[1];
    float mav[8] = {ma0.x, ma0.y, ma0.z, ma0.w, ma1.x, ma1.y, ma1.z, ma1.w};
    float s1[8], s2[8];
    #pragma unroll
    for (int jj = 0; jj < 8; ++jj) {
      const float4* kf = (const float4*)&Kl[(j0 + jj) * KDIM];
      float4 k0 = kf[0], k1 = kf[1], k2 = kf[2], k3 = kf[3];
      float d1a = q1[0] * k0.x + q1[1] * k0.y + q1[2] * k0.z + q1[3] * k0.w
                + q1[4] * k1.x + q1[5] * k1.y + q1[6] * k1.z + q1[7] * k1.w;
      float d1b = q1[8] * k2.x + q1[9] * k2.y + q1[10] * k2.z + q1[11] * k2.w
                + q1[12] * k3.x + q1[13] * k3.y + q1[14] * k3.z + q1[15] * k3.w;
      float d2a = q2[0] * k0.x + q2[1] * k0.y + q2[2] * k0.z + q2[3] * k0.w
                + q2[4] * k1.x + q2[5] * k1.y + q2[6] * k1.z + q2[7] * k1.w;
      float d2b = q2[8] * k2.x + q2[9] * k2.y + q2[10] * k2.z + q2[11] * k2.w
                + q2[12] * k3.x + q2[13] * k3.y + q2[14] * k3.z + q2[15] * k3.w;
      s1[jj] = d1a + d1b + mav[jj];
      s2[jj] = d2a + d2b + mav[jj];
    }
    float cm1 = s1[0], cm2 = s2[0];
    #pragma unroll
    for (int jj = 1; jj < 8; ++jj) { cm1 = fmaxf(cm1, s1[jj]); cm2 = fmaxf(cm2, s2[jj]); }
    float nm1 = fmaxf(m1, cm1), nm2 = fmaxf(m2, cm2);
    float sc1 = __expf(m1 - nm1), sc2 = __expf(m2 - nm2);
    ls1 *= sc1; ls2 *= sc2;
    #pragma unroll
    for (int t = 0; t < KDIM; ++t) { acc1[t] *= sc1; acc2[t] *= sc2; }
    #pragma unroll
    for (int jj = 0; jj < 8; ++jj) {
      float p1 = __expf(s1[jj] - nm1);
      float p2 = __expf(s2[jj] - nm2);
      ls1 += p1; ls2 += p2;
      const float4* vf = (const float4*)&Vl[(j0 + jj) * KDIM];
      float4 v0 = vf[0], v1 = vf[1], v2 = vf[2], v3 = vf[3];
      acc1[0] += p1 * v0.x;  acc1[1] += p1 * v0.y;  acc1[2] += p1 * v0.z;  acc1[3] += p1 * v0.w;
      acc1[4] += p1 * v1.x;  acc1[5] += p1 * v1.y;  acc1[6] += p1 * v1.z;  acc1[7] += p1 * v1.w;
      acc1[8] += p1 * v2.x;  acc1[9] += p1 * v2.y;  acc1[10] += p1 * v2.z; acc1[11] += p1 * v2.w;
      acc1[12] += p1 * v3.x; acc1[13] += p1 * v3.y; acc1[14] += p1 * v3.z; acc1[15] += p1 * v3.w;
      acc2[0] += p2 * v0.x;  acc2[1] += p2 * v0.y;  acc2[2] += p2 * v0.z;  acc2[3] += p2 * v0.w;
      acc2[4] += p2 * v1.x;  acc2[5] += p2 * v1.y;  acc2[6] += p2 * v1.z;  acc2[7] += p2 * v1.w;
      acc2[8] += p2 * v2.x;  acc2[9] += p2 * v2.y;  acc2[10] += p2 * v2.z; acc2[11] += p2 * v2.w;
      acc2[12] += p2 * v3.x; acc2[13] += p2 * v3.y; acc2[14] += p2 * v3.z; acc2[15] += p2 * v3.w;
    }
    m1 = nm1; m2 = nm2;
  }
  if (a1) {
    float inv = 1.0f / ls1;
    #pragma unroll
    for (int t = 0; t < KDIM; ++t)
      op[base + (size_t)t * L + i1] = acc1[t] * inv;
  }
  if (a2) {
    float inv = 1.0f / ls2;
    #pragma unroll
    for (int t = 0; t < KDIM; ++t)
      op[base + (size_t)t * L + i2] = acc2[t] * inv;
  }
}

// ---------------- [B,D,L] -> [B,L,D] transpose ----------------
__global__ void k_transpose(const float* __restrict__ X, float* __restrict__ Y,
                            int L, int total) {
  int idx = blockIdx.x * 256 + threadIdx.x;
  if (idx >= total) return;
  int d = idx % DD;
  int l = (idx / DD) % L;
  int b = idx / (DD * L);
  Y[idx] = X[((size_t)b * DD + d) * L + l];
}

// ---------------- dot over D: out[b,l] = sum_d X[b,d,l]*w[d] ----------------
__global__ void k_dotD(const float* __restrict__ X, const float* __restrict__ w,
                       float* __restrict__ out, int L, int total) {
  int idx = blockIdx.x * 256 + threadIdx.x;
  if (idx >= total) return;
  int l = idx % L;
  int b = idx / L;
  const float* px = X + (size_t)b * DD * L + l;
  float acc = 0.f;
  for (int d = 0; d < DD; ++d) acc += px[(size_t)d * L] * w[d];
  out[idx] = acc;
}

// ---------------- S[b,n,m] trilinear ----------------
__global__ void k_S(const float* __restrict__ C, const float* __restrict__ Qf,
                    const float* __restrict__ cd, const float* __restrict__ qd,
                    const float* __restrict__ wm, const float* __restrict__ bias,
                    float* __restrict__ S) {
  int idx = blockIdx.x * 256 + threadIdx.x;
  if (idx >= BB * NN * MM) return;
  int mcol = idx % MM;
  int n = (idx / MM) % NN;
  int b = idx / (MM * NN);
  const float* pc = C + (size_t)b * DD * NN + n;
  const float* pq = Qf + (size_t)b * DD * MM + mcol;
  float acc = 0.f;
  for (int d = 0; d < DD; ++d)
    acc += pc[(size_t)d * NN] * wm[d] * pq[(size_t)d * MM];
  S[idx] = acc + cd[b * NN + n] + qd[b * MM + mcol] + bias[0];
}

// ---------------- softmax over n (col) -> Sc; 1 wave per (b,m) ----------------
__global__ void k_smax_col(const float* __restrict__ S, const float* __restrict__ cmask,
                           float* __restrict__ Sc) {
  int b = blockIdx.x / MM;
  int mcol = blockIdx.x % MM;
  int tid = threadIdx.x;
  float vals[7];
  float mx = -1e30f;
  #pragma unroll
  for (int c = 0; c < 7; ++c) {
    int n = tid + c * 64;
    float s = -1e30f;
    if (n < NN)
      s = S[((size_t)b * NN + n) * MM + mcol] - 1e30f * (1.0f - cmask[b * NN + n]);
    vals[c] = s;
    mx = fmaxf(mx, s);
  }
  #pragma unroll
  for (int off = 1; off < 64; off <<= 1) mx = fmaxf(mx, __shfl_xor(mx, off));
  float sum = 0.f;
  #pragma unroll
  for (int c = 0; c < 7; ++c) { vals[c] = __expf(vals[c] - mx); sum += vals[c]; }
  #pragma unroll
  for (int off = 1; off < 64; off <<= 1) sum += __shfl_xor(sum, off);
  float inv = 1.0f / sum;
  #pragma unroll
  for (int c = 0; c < 7; ++c) {
    int n = tid + c * 64;
    if (n < NN) Sc[((size_t)b * NN + n) * MM + mcol] = vals[c] * inv;
  }
}

// ---------------- softmax over m (row), in-place; 1 wave per (b,n) ----------------
__global__ void k_smax_row(float* __restrict__ S, const float* __restrict__ qmask) {
  int bn = blockIdx.x;
  int b = bn / NN;
  int tid = threadIdx.x;
  float s = -1e30f;
  if (tid < MM)
    s = S[(size_t)bn * MM + tid] - 1e30f * (1.0f - qmask[b * MM + tid]);
  float mx = s;
  #pragma unroll
  for (int off = 1; off < 64; off <<= 1) mx = fmaxf(mx, __shfl_xor(mx, off));
  float e = (tid < MM) ? __expf(s - mx) : 0.f;
  float sum = e;
  #pragma unroll
  for (int off = 1; off < 64; off <<= 1) sum += __shfl_xor(sum, off);
  if (tid < MM) S[(size_t)bn * MM + tid] = e / sum;
}

// ---------------- U[b,m,d] = sum_k Sc[b,k,m]*C2[b,k,d] ----------------
__global__ void k_U(const float* __restrict__ Sc, const float* __restrict__ C2,
                    float* __restrict__ U) {
  int idx = blockIdx.x * 256 + threadIdx.x;
  if (idx >= BB * MM * DD) return;
  int d = idx % DD;
  int mcol = (idx / DD) % MM;
  int b = idx / (DD * MM);
  const float* psc = Sc + (size_t)b * NN * MM + mcol;
  const float* pc2 = C2 + (size_t)b * NN * DD + d;
  float acc = 0.f;
  for (int kk = 0; kk < NN; ++kk)
    acc += psc[(size_t)kk * MM] * pc2[(size_t)kk * DD];
  U[idx] = acc;
}

// ---------------- A, Bt = Sr @ {Q2, U} ----------------
__global__ void k_ABt(const float* __restrict__ Sr, const float* __restrict__ Q2,
                      const float* __restrict__ Uu, float* __restrict__ A,
                      float* __restrict__ Bt) {
  int idx = blockIdx.x * 256 + threadIdx.x;
  if (idx >= BB * NN * DD) return;
  int d = idx % DD;
  int n = (idx / DD) % NN;
  int b = idx / (DD * NN);
  const float* ps = Sr + ((size_t)b * NN + n) * MM;
  const float* pq = Q2 + (size_t)b * MM * DD + d;
  const float* pu = Uu + (size_t)b * MM * DD + d;
  float a = 0.f, bt = 0.f;
  for (int mcol = 0; mcol < MM; ++mcol) {
    float s = ps[mcol];
    a += s * pq[(size_t)mcol * DD];
    bt += s * pu[(size_t)mcol * DD];
  }
  A[idx] = a; Bt[idx] = bt;
}

// ---------------- final concat [C2, A, C2*A, C2*Bt] ----------------
__global__ void k_final(const float* __restrict__ C2, const float* __restrict__ A,
                        const float* __restrict__ Bt, float* __restrict__ out) {
  int idx = blockIdx.x * 256 + threadIdx.x;
  if (idx >= BB * NN * DD) return;
  int d = idx % DD;
  int bn = idx / DD;
  float c = C2[idx], a = A[idx], bt = Bt[idx];
  float* po = out + (size_t)bn * 512;
  po[d] = c;
  po[128 + d] = a;
  po[256 + d] = c * a;
  po[384 + d] = c * bt;
}

extern "C" void kernel_launch(void* const* d_in, const int* in_sizes, int n_in,
                              void* d_out, int out_size, void* d_ws, size_t ws_size,
                              hipStream_t stream) {
  (void)in_sizes; (void)n_in; (void)out_size; (void)ws_size;
  const float* ctx   = (const float*)d_in[0];
  const float* que   = (const float*)d_in[1];
  const float* cmask = (const float*)d_in[2];
  const float* qmask = (const float*)d_in[3];
  const float* ln_g  = (const float*)d_in[4];
  const float* ln_b  = (const float*)d_in[5];
  const float* dw_w  = (const float*)d_in[6];
  const float* dw_b  = (const float*)d_in[7];
  const float* pw_w  = (const float*)d_in[8];
  const float* pw_b  = (const float*)d_in[9];
  const float* Wq    = (const float*)d_in[10];
  const float* bq    = (const float*)d_in[11];
  const float* Wk    = (const float*)d_in[12];
  const float* bk    = (const float*)d_in[13];
  const float* Wv    = (const float*)d_in[14];
  const float* bv    = (const float*)d_in[15];
  const float* Wo    = (const float*)d_in[16];
  const float* bo    = (const float*)d_in[17];
  const float* Wfc   = (const float*)d_in[18];
  const float* bfc   = (const float*)d_in[19];
  const float* cq_wc = (const float*)d_in[20];
  const float* cq_wq = (const float*)d_in[21];
  const float* cq_wm = (const float*)d_in[22];
  const float* cq_b  = (const float*)d_in[23];
  float* out = (float*)d_out;
  float* ws = (float*)d_ws;

  float* Cb   = ws;
  float* Qb   = Cb + SZ_C;
  float* t1C  = Qb + SZ_Q;
  float* t1Q  = t1C + SZ_C;
  float* t2C  = t1Q + SZ_Q;
  float* t2Q  = t2C + SZ_C;
  float* t3C  = t2Q + SZ_Q;
  float* t3Q  = t3C + SZ_C;
  float* t4C  = t3Q + SZ_Q;
  float* t4Q  = t4C + SZ_C;
  float* muB  = t4Q + SZ_Q;
  float* invB = muB + SSTAT;
  float* Wcan = invB + SSTAT;
  // Wcan: 9*16384 floats; total ws usage ~74.5 MB

  int totAll = SZ_C + SZ_Q;
  int nbAll = (totAll + 255) / 256;

  k_transposeW<<<(9 * 16384 + 255) / 256, 256, 0, stream>>>(pw_w, Wo, Wfc, Wq, Wk, Wv, Wcan);
  k_pe<<<nbAll, 256, 0, stream>>>(ctx, que, Cb, Qb);

  for (int i = 0; i < NC; ++i) {
    k_lnstats<<<512, 256, 0, stream>>>(Cb, Qb, muB, invB);
    k_dw<<<nbAll, 256, 0, stream>>>(Cb, Qb, t1C, t1Q,
                                    dw_w + (size_t)i * DD * KW, dw_b + (size_t)i * DD,
                                    muB, invB, ln_g, ln_b);
    k_gemm128<0, 2><<<320, 256, 0, stream>>>(t1C, t1Q, Cb, Qb,
                                             Wcan + (size_t)i * 16384, pw_b + (size_t)i * DD,
                                             muB, invB, ln_g, ln_b);
  }
  // self-attention
  k_lnstats<<<512, 256, 0, stream>>>(Cb, Qb, muB, invB);
  k_gemm128<1, 0><<<320, 256, 0, stream>>>(Cb, Qb, t1C, t1Q, Wcan + 6 * 16384, bq,
                                           muB, invB, ln_g, ln_b);
  k_gemm128<1, 0><<<320, 256, 0, stream>>>(Cb, Qb, t2C, t2Q, Wcan + 7 * 16384, bk,
                                           muB, invB, ln_g, ln_b);
  k_gemm128<1, 0><<<320, 256, 0, stream>>>(Cb, Qb, t3C, t3Q, Wcan + 8 * 16384, bv,
                                           muB, invB, ln_g, ln_b);
  k_attn2<<<1024, 256, 0, stream>>>(t1C, t2C, t3C, t1Q, t2Q, t3Q, cmask, qmask, t4C, t4Q);
  k_gemm128<0, 1><<<320, 256, 0, stream>>>(t4C, t4Q, Cb, Qb, Wcan + 4 * 16384, bo,
                                           muB, invB, ln_g, ln_b);
  // FFN (in-place residual: each block reads its full x-region before writing)
  k_lnstats<<<512, 256, 0, stream>>>(Cb, Qb, muB, invB);
  k_gemm128<1, 1><<<320, 256, 0, stream>>>(Cb, Qb, Cb, Qb, Wcan + 5 * 16384, bfc,
                                           muB, invB, ln_g, ln_b);

  // ---- context-query attention ----
  float* C2  = t1C;
  float* Q2  = t1Q;
  float* S   = t2C;
  float* Scb = t3C;
  float* Uu  = t2Q;
  float* cd  = t3Q;
  float* qd  = t4Q;
  float* A   = t4C;
  float* Bt  = Cb;  // Cb free after its readers below

  int totC = BB * NN * DD;
  int totQ = BB * MM * DD;
  k_transpose<<<(totC + 255) / 256, 256, 0, stream>>>(Cb, C2, NN, totC);
  k_transpose<<<(totQ + 255) / 256, 256, 0, stream>>>(Qb, Q2, MM, totQ);
  k_dotD<<<(BB * NN + 255) / 256, 256, 0, stream>>>(Cb, cq_wc, cd, NN, BB * NN);
  k_dotD<<<(BB * MM + 255) / 256, 256, 0, stream>>>(Qb, cq_wq, qd, MM, BB * MM);
  k_S<<<(BB * NN * MM + 255) / 256, 256, 0, stream>>>(Cb, Qb, cd, qd, cq_wm, cq_b, S);
  k_smax_col<<<BB * MM, 64, 0, stream>>>(S, cmask, Scb);
  k_smax_row<<<BB * NN, 64, 0, stream>>>(S, qmask); // S now holds S_r
  k_U<<<(BB * MM * DD + 255) / 256, 256, 0, stream>>>(Scb, C2, Uu);
  k_ABt<<<(totC + 255) / 256, 256, 0, stream>>>(S, Q2, Uu, A, Bt);
  k_final<<<(totC + 255) / 256, 256, 0, stream>>>(C2, A, Bt, out);
}

// Round 2
// 1006.630 us; speedup vs baseline: 1.1199x; 1.0751x over previous
//
#include <hip/hip_runtime.h>
#include <math.h>

#define BB 64
#define DD 128
#define NN 400
#define MM 50
#define HH 8
#define KDIM 16
#define NC 4
#define KW 7

#define SZ_C (BB * DD * NN)   // 3,276,800
#define SZ_Q (BB * DD * MM)   //   409,600
#define SSTAT (BB * NN + BB * MM)  // 28,800; q stats at offset BB*NN

// ---------------- canonical weight transpose: Wcan[m][d][e] ----------------
// m 0..3: pw_w (e-major), m 4: Wo (d-major, copy), m 5: Wfc (e-major),
// m 6..8: Wq/Wk/Wv ([h][d][kd], e = h*16+kd)
__global__ void k_transposeW(const float* __restrict__ pw_w, const float* __restrict__ Wo,
                             const float* __restrict__ Wfc, const float* __restrict__ Wq,
                             const float* __restrict__ Wk, const float* __restrict__ Wv,
                             float* __restrict__ Wcan) {
  int idx = blockIdx.x * 256 + threadIdx.x;
  if (idx >= 9 * 16384) return;
  int m = idx >> 14;
  int r = idx & 16383;
  int d = r >> 7, e = r & 127;
  float v;
  if (m < 4) v = pw_w[m * 16384 + e * 128 + d];
  else if (m == 4) v = Wo[d * 128 + e];
  else if (m == 5) v = Wfc[e * 128 + d];
  else {
    const float* W = (m == 6) ? Wq : (m == 7) ? Wk : Wv;
    v = W[((e >> 4) * 128 + d) * 16 + (e & 15)];
  }
  Wcan[idx] = v;
}

// ---------------- position encoding add (both phases) ----------------
__global__ void k_pe(const float* __restrict__ xC, const float* __restrict__ xQ,
                     float* __restrict__ yC, float* __restrict__ yQ) {
  int idx = blockIdx.x * 256 + threadIdx.x;
  const float* x; float* y; int L, id2;
  if (idx < SZ_C) { x = xC; y = yC; L = NN; id2 = idx; }
  else if (idx < SZ_C + SZ_Q) { x = xQ; y = yQ; L = MM; id2 = idx - SZ_C; }
  else return;
  int l = id2 % L;
  int d = (id2 / L) % DD;
  int de = d & ~1;
  float freq = __expf((float)de * (-9.210340371976184f / 128.0f));
  float phase = (d & 1) ? 1.5707963267948966f : 0.0f;
  y[id2] = x[id2] + sinf((float)l * freq + phase);
}

// ---------------- LN stats: mu and 1/(sd+eps), ddof=1 ----------------
__global__ void k_lnstats(const float* __restrict__ xC, const float* __restrict__ xQ,
                          float* __restrict__ mu, float* __restrict__ inv) {
  int blk = blockIdx.x;
  const float* x; int L, lt, b, soff;
  if (blk < 448) { b = blk / 7; lt = blk % 7; x = xC; L = NN; soff = 0; }
  else { b = blk - 448; lt = 0; x = xQ; L = MM; soff = BB * NN; }
  int ll = threadIdx.x & 63;
  int dq = threadIdx.x >> 6;
  int l = lt * 64 + ll;
  __shared__ float s_sum[4][64], s_sq[4][64];
  float sum = 0.f, sq = 0.f;
  const float* px = x + (size_t)b * DD * L + l;
  if (l < L) {
    for (int d = dq * 32; d < dq * 32 + 32; ++d) {
      float v = px[(size_t)d * L];
      sum += v; sq += v * v;
    }
  }
  s_sum[dq][ll] = sum; s_sq[dq][ll] = sq;
  __syncthreads();
  if (dq == 0 && l < L) {
    float ts = s_sum[0][ll] + s_sum[1][ll] + s_sum[2][ll] + s_sum[3][ll];
    float tq = s_sq[0][ll] + s_sq[1][ll] + s_sq[2][ll] + s_sq[3][ll];
    float m = ts * (1.0f / 128.0f);
    float var = (tq - 128.0f * m * m) * (1.0f / 127.0f);
    float sd = sqrtf(fmaxf(var, 0.f));
    mu[soff + b * L + l] = m;
    inv[soff + b * L + l] = 1.0f / (sd + 1e-6f);
  }
}

// ---------------- depthwise conv K=7 pad=3, LN fused (both phases) ----------------
__global__ void k_dw(const float* __restrict__ xC, const float* __restrict__ xQ,
                     float* __restrict__ yC, float* __restrict__ yQ,
                     const float* __restrict__ w, const float* __restrict__ bias,
                     const float* __restrict__ mu, const float* __restrict__ inv,
                     const float* __restrict__ g, const float* __restrict__ beta) {
  int idx = blockIdx.x * 256 + threadIdx.x;
  const float* x; float* y; int L, id2, soff;
  if (idx < SZ_C) { x = xC; y = yC; L = NN; id2 = idx; soff = 0; }
  else if (idx < SZ_C + SZ_Q) { x = xQ; y = yQ; L = MM; id2 = idx - SZ_C; soff = BB * NN; }
  else return;
  int l = id2 % L;
  int d = (id2 / L) % DD;
  int b = id2 / (DD * L);
  const float* px = x + (size_t)(id2 - l);
  const float* pmu = mu + soff + b * L;
  const float* pin = inv + soff + b * L;
  float gd = g[d], bd = beta[d];
  float acc = bias[d];
  #pragma unroll
  for (int k = 0; k < KW; ++k) {
    int lt = l + k - 3;
    if (lt >= 0 && lt < L) {
      float v = gd * (px[lt] - pmu[lt]) * pin[lt] + bd;
      acc += v * w[d * KW + k];
    }
  }
  y[id2] = acc;
}

// ---------------- 128x128 GEMM over [B,128,L], both phases ----------------
template <int LNF, int ACT>
__global__ __launch_bounds__(256) void k_gemm128(
    const float* __restrict__ xC, const float* __restrict__ xQ,
    float* __restrict__ outC, float* __restrict__ outQ,
    const float* __restrict__ Wc, const float* __restrict__ bias,
    const float* __restrict__ mu, const float* __restrict__ inv,
    const float* __restrict__ g, const float* __restrict__ beta) {
  int blk = blockIdx.x;
  int b = blk / 5, tile = blk % 5;
  const float* x; float* out; int L, l0, soff;
  if (tile < 4) { x = xC; out = outC; L = NN; l0 = tile * 128; soff = 0; }
  else { x = xQ; out = outQ; L = MM; l0 = 0; soff = BB * NN; }
  __shared__ float Wl[32 * 128];
  __shared__ float Xl[32 * 128];
  int tid = threadIdx.x;
  float acc[8][8];
  #pragma unroll
  for (int i = 0; i < 8; ++i)
    #pragma unroll
    for (int j = 0; j < 8; ++j) acc[i][j] = 0.f;
  const float* xb = x + (size_t)b * DD * L;
  const float* pmu = mu + soff + b * L;
  const float* pin = inv + soff + b * L;
  for (int kc = 0; kc < 4; ++kc) {
    int d0 = kc * 32;
    #pragma unroll
    for (int i = 0; i < 16; ++i) {
      int idx = i * 256 + tid;
      Wl[idx] = Wc[(size_t)(d0 + (idx >> 7)) * 128 + (idx & 127)];
    }
    #pragma unroll
    for (int i = 0; i < 16; ++i) {
      int idx = i * 256 + tid;
      int k = idx >> 7, l = idx & 127;
      float v = 0.f;
      if (l0 + l < L) {
        v = xb[(size_t)(d0 + k) * L + l0 + l];
        if (LNF) v = g[d0 + k] * (v - pmu[l0 + l]) * pin[l0 + l] + beta[d0 + k];
      }
      Xl[idx] = v;
    }
    __syncthreads();
    int e0 = (tid >> 4) * 8, lq = (tid & 15) * 8;
    for (int k = 0; k < 32; ++k) {
      const float4* wp = (const float4*)&Wl[k * 128 + e0];
      const float4* xp = (const float4*)&Xl[k * 128 + lq];
      float4 w0 = wp[0], w1 = wp[1], x0 = xp[0], x1 = xp[1];
      float we[8] = {w0.x, w0.y, w0.z, w0.w, w1.x, w1.y, w1.z, w1.w};
      float xe[8] = {x0.x, x0.y, x0.z, x0.w, x1.x, x1.y, x1.z, x1.w};
      #pragma unroll
      for (int i = 0; i < 8; ++i)
        #pragma unroll
        for (int j = 0; j < 8; ++j) acc[i][j] += we[i] * xe[j];
    }
    __syncthreads();
  }
  int e0 = (tid >> 4) * 8, lq = l0 + (tid & 15) * 8;
  #pragma unroll
  for (int i = 0; i < 8; ++i) {
    float bi = bias[e0 + i];
    float* po = out + ((size_t)b * DD + e0 + i) * L;
    #pragma unroll
    for (int j = 0; j < 8; ++j) {
      int l = lq + j;
      if (l < L) {
        float v = acc[i][j] + bi;
        if (ACT == 2) v = fmaxf(v, 0.f);
        if (ACT == 0) po[l] = v;
        else po[l] = v + po[l];
      }
    }
  }
}

// ---------------- fused QKV GEMM: 3 weight sets in one launch ----------------
__global__ __launch_bounds__(256) void k_gemm_qkv(
    const float* __restrict__ xC, const float* __restrict__ xQ,
    float* __restrict__ o1C, float* __restrict__ o1Q,
    float* __restrict__ o2C, float* __restrict__ o2Q,
    float* __restrict__ o3C, float* __restrict__ o3Q,
    const float* __restrict__ Wcan,
    const float* __restrict__ bq, const float* __restrict__ bk, const float* __restrict__ bv,
    const float* __restrict__ mu, const float* __restrict__ inv,
    const float* __restrict__ g, const float* __restrict__ beta) {
  int blk0 = blockIdx.x;
  int grp = blk0 / 320;
  int blk = blk0 - grp * 320;
  const float* Wc = Wcan + (size_t)(6 + grp) * 16384;
  const float* bias = (grp == 0) ? bq : (grp == 1) ? bk : bv;
  float* oC = (grp == 0) ? o1C : (grp == 1) ? o2C : o3C;
  float* oQ = (grp == 0) ? o1Q : (grp == 1) ? o2Q : o3Q;
  int b = blk / 5, tile = blk % 5;
  const float* x; float* out; int L, l0, soff;
  if (tile < 4) { x = xC; out = oC; L = NN; l0 = tile * 128; soff = 0; }
  else { x = xQ; out = oQ; L = MM; l0 = 0; soff = BB * NN; }
  __shared__ float Wl[32 * 128];
  __shared__ float Xl[32 * 128];
  int tid = threadIdx.x;
  float acc[8][8];
  #pragma unroll
  for (int i = 0; i < 8; ++i)
    #pragma unroll
    for (int j = 0; j < 8; ++j) acc[i][j] = 0.f;
  const float* xb = x + (size_t)b * DD * L;
  const float* pmu = mu + soff + b * L;
  const float* pin = inv + soff + b * L;
  for (int kc = 0; kc < 4; ++kc) {
    int d0 = kc * 32;
    #pragma unroll
    for (int i = 0; i < 16; ++i) {
      int idx = i * 256 + tid;
      Wl[idx] = Wc[(size_t)(d0 + (idx >> 7)) * 128 + (idx & 127)];
    }
    #pragma unroll
    for (int i = 0; i < 16; ++i) {
      int idx = i * 256 + tid;
      int k = idx >> 7, l = idx & 127;
      float v = 0.f;
      if (l0 + l < L) {
        v = xb[(size_t)(d0 + k) * L + l0 + l];
        v = g[d0 + k] * (v - pmu[l0 + l]) * pin[l0 + l] + beta[d0 + k];
      }
      Xl[idx] = v;
    }
    __syncthreads();
    int e0 = (tid >> 4) * 8, lq = (tid & 15) * 8;
    for (int k = 0; k < 32; ++k) {
      const float4* wp = (const float4*)&Wl[k * 128 + e0];
      const float4* xp = (const float4*)&Xl[k * 128 + lq];
      float4 w0 = wp[0], w1 = wp[1], x0 = xp[0], x1 = xp[1];
      float we[8] = {w0.x, w0.y, w0.z, w0.w, w1.x, w1.y, w1.z, w1.w};
      float xe[8] = {x0.x, x0.y, x0.z, x0.w, x1.x, x1.y, x1.z, x1.w};
      #pragma unroll
      for (int i = 0; i < 8; ++i)
        #pragma unroll
        for (int j = 0; j < 8; ++j) acc[i][j] += we[i] * xe[j];
    }
    __syncthreads();
  }
  int e0 = (tid >> 4) * 8, lq = l0 + (tid & 15) * 8;
  #pragma unroll
  for (int i = 0; i < 8; ++i) {
    float bi = bias[e0 + i];
    float* po = out + ((size_t)b * DD + e0 + i) * L;
    #pragma unroll
    for (int j = 0; j < 8; ++j) {
      int l = lq + j;
      if (l < L) po[l] = acc[i][j] + bi;
    }
  }
}

// ---------------- attention ----------------
// ctx: 2 blocks per (b,h) splitting the 400 queries [0,256)/[256,400);
// 1 query per thread, inactive threads exit right after staging (no later syncs).
// Rescale branch is exact: skipped iff new chunk max <= running max (factor==1).
__global__ __launch_bounds__(256) void k_attn2(
    const float* __restrict__ qC, const float* __restrict__ kC, const float* __restrict__ vC,
    const float* __restrict__ qQ, const float* __restrict__ kQ, const float* __restrict__ vQ,
    const float* __restrict__ cmask, const float* __restrict__ qmask,
    float* __restrict__ oC, float* __restrict__ oQ) {
  int blk = blockIdx.x;
  const float *qp, *kp, *vp, *mk; float* op; int L, b, h, q0, qcnt;
  if (blk < 1024) {
    b = blk >> 4; h = (blk >> 1) & 7; int half = blk & 1;
    qp = qC; kp = kC; vp = vC; mk = cmask; op = oC; L = NN;
    q0 = half * 256; qcnt = half ? (NN - 256) : 256;
  } else {
    int bb = blk - 1024; b = bb >> 3; h = bb & 7;
    qp = qQ; kp = kQ; vp = vQ; mk = qmask; op = oQ; L = MM;
    q0 = 0; qcnt = MM;
  }
  __shared__ float Kl[NN * KDIM];
  __shared__ float Vl[NN * KDIM];
  __shared__ float Ml[NN];  // staged additive mask: -1e30*(1-m), -1e30 in pad rows
  int tid = threadIdx.x;
  size_t base = ((size_t)b * DD + h * KDIM) * L;
  int KP = (L + 7) & ~7;  // 400 -> 400, 50 -> 56
  for (int idx = tid; idx < KDIM * L; idx += 256) {
    int t = idx / L, j = idx - t * L;
    Kl[j * KDIM + t] = kp[base + (size_t)t * L + j];
    Vl[j * KDIM + t] = vp[base + (size_t)t * L + j];
  }
  for (int idx = tid; idx < (KP - L) * KDIM; idx += 256) {
    int j = L + (idx >> 4), t = idx & 15;
    Kl[j * KDIM + t] = 0.f; Vl[j * KDIM + t] = 0.f;
  }
  for (int j = tid; j < KP; j += 256)
    Ml[j] = (j < L) ? -1e30f * (1.0f - mk[b * L + j]) : -1e30f;
  __syncthreads();
  if (tid >= qcnt) return;  // no further syncs: legal early exit

  int i = q0 + tid;
  float q[KDIM];
  #pragma unroll
  for (int t = 0; t < KDIM; ++t) q[t] = qp[base + (size_t)t * L + i] * 0.25f;
  float m = -1e30f, ls = 0.f;
  float acc[KDIM];
  #pragma unroll
  for (int t = 0; t < KDIM; ++t) acc[t] = 0.f;
  for (int j0 = 0; j0 < KP; j0 += 8) {
    const float4* mp = (const float4*)&Ml[j0];
    float4 ma0 = mp[0], ma1 = mp[1];
    float mav[8] = {ma0.x, ma0.y, ma0.z, ma0.w, ma1.x, ma1.y, ma1.z, ma1.w};
    float s[8];
    #pragma unroll
    for (int jj = 0; jj < 8; ++jj) {
      const float4* kf = (const float4*)&Kl[(j0 + jj) * KDIM];
      float4 k0 = kf[0], k1 = kf[1], k2 = kf[2], k3 = kf[3];
      float da = q[0] * k0.x + q[1] * k0.y + q[2] * k0.z + q[3] * k0.w
               + q[4] * k1.x + q[5] * k1.y + q[6] * k1.z + q[7] * k1.w;
      float db = q[8] * k2.x + q[9] * k2.y + q[10] * k2.z + q[11] * k2.w
               + q[12] * k3.x + q[13] * k3.y + q[14] * k3.z + q[15] * k3.w;
      s[jj] = da + db + mav[jj];
    }
    float cm = s[0];
    #pragma unroll
    for (int jj = 1; jj < 8; ++jj) cm = fmaxf(cm, s[jj]);
    if (cm > m) {  // exact: skipped branch would multiply by exp(0)=1
      float sc = __expf(m - cm);
      ls *= sc;
      #pragma unroll
      for (int t = 0; t < KDIM; ++t) acc[t] *= sc;
      m = cm;
    }
    #pragma unroll
    for (int jj = 0; jj < 8; ++jj) {
      float p = __expf(s[jj] - m);
      ls += p;
      const float4* vf = (const float4*)&Vl[(j0 + jj) * KDIM];
      float4 v0 = vf[0], v1 = vf[1], v2 = vf[2], v3 = vf[3];
      acc[0] += p * v0.x;  acc[1] += p * v0.y;  acc[2] += p * v0.z;  acc[3] += p * v0.w;
      acc[4] += p * v1.x;  acc[5] += p * v1.y;  acc[6] += p * v1.z;  acc[7] += p * v1.w;
      acc[8] += p * v2.x;  acc[9] += p * v2.y;  acc[10] += p * v2.z; acc[11] += p * v2.w;
      acc[12] += p * v3.x; acc[13] += p * v3.y; acc[14] += p * v3.z; acc[15] += p * v3.w;
    }
  }
  float invl = 1.0f / ls;
  #pragma unroll
  for (int t = 0; t < KDIM; ++t)
    op[base + (size_t)t * L + i] = acc[t] * invl;
}

// ---------------- fused prep: tiled transposes + dotD (4 jobs, 1 launch) ----------------
// blocks [0,3328): C transpose; [3328,3840): Q transpose; [3840,3940): dotD C; [3940,3953): dotD Q
__global__ void k_prep(const float* __restrict__ Cb, const float* __restrict__ Qb,
                       float* __restrict__ C2, float* __restrict__ Q2,
                       const float* __restrict__ wc, const float* __restrict__ wq,
                       float* __restrict__ cd, float* __restrict__ qd) {
  int blk = blockIdx.x, tid = threadIdx.x;
  if (blk < 3840) {
    const float* X; float* Y; int L, rem;
    if (blk < 3328) { X = Cb; Y = C2; L = NN; rem = blk; }
    else { X = Qb; Y = Q2; L = MM; rem = blk - 3328; }
    int ntl = (L + 31) / 32;
    int b = rem / (4 * ntl);
    int r2 = rem % (4 * ntl);
    int d0 = (r2 / ntl) * 32;
    int l0 = (r2 % ntl) * 32;
    __shared__ float T[32][33];
    int c = tid & 31, r8 = tid >> 5;
    const float* xb = X + (size_t)b * DD * L;
    #pragma unroll
    for (int k = 0; k < 4; ++k) {
      int r = r8 + k * 8;  // d offset
      int l = l0 + c;
      T[r][c] = (l < L) ? xb[(size_t)(d0 + r) * L + l] : 0.f;
    }
    __syncthreads();
    float* yb = Y + (size_t)b * L * DD;
    #pragma unroll
    for (int k = 0; k < 4; ++k) {
      int rr = r8 + k * 8;  // l offset
      int l = l0 + rr;
      if (l < L) yb[(size_t)l * DD + d0 + c] = T[c][rr];
    }
  } else if (blk < 3940) {
    int idx = (blk - 3840) * 256 + tid;
    if (idx < BB * NN) {
      int l = idx % NN, b = idx / NN;
      const float* px = Cb + (size_t)b * DD * NN + l;
      float acc = 0.f;
      for (int d = 0; d < DD; ++d) acc += px[(size_t)d * NN] * wc[d];
      cd[idx] = acc;
    }
  } else {
    int idx = (blk - 3940) * 256 + tid;
    if (idx < BB * MM) {
      int l = idx % MM, b = idx / MM;
      const float* px = Qb + (size_t)b * DD * MM + l;
      float acc = 0.f;
      for (int d = 0; d < DD; ++d) acc += px[(size_t)d * MM] * wq[d];
      qd[idx] = acc;
    }
  }
}

// ---------------- S[b,n,m] trilinear (reads row-major C2/Q2, float4) ----------------
__global__ void k_S(const float* __restrict__ C2, const float* __restrict__ Q2,
                    const float* __restrict__ cd, const float* __restrict__ qd,
                    const float* __restrict__ wm, const float* __restrict__ bias,
                    float* __restrict__ S) {
  int idx = blockIdx.x * 256 + threadIdx.x;
  if (idx >= BB * NN * MM) return;
  int mcol = idx % MM;
  int n = (idx / MM) % NN;
  int b = idx / (MM * NN);
  const float4* pc = (const float4*)(C2 + ((size_t)b * NN + n) * DD);
  const float4* pq = (const float4*)(Q2 + ((size_t)b * MM + mcol) * DD);
  const float4* pw = (const float4*)wm;
  float a0 = 0.f, a1 = 0.f;
  #pragma unroll 4
  for (int d4 = 0; d4 < 32; d4 += 2) {
    float4 c0 = pc[d4], w0 = pw[d4], q0 = pq[d4];
    float4 c1 = pc[d4 + 1], w1 = pw[d4 + 1], q1 = pq[d4 + 1];
    a0 += (c0.x * w0.x) * q0.x + (c0.y * w0.y) * q0.y + (c0.z * w0.z) * q0.z + (c0.w * w0.w) * q0.w;
    a1 += (c1.x * w1.x) * q1.x + (c1.y * w1.y) * q1.y + (c1.z * w1.z) * q1.z + (c1.w * w1.w) * q1.w;
  }
  S[idx] = a0 + a1 + cd[b * NN + n] + qd[b * MM + mcol] + bias[0];
}

// ---------------- merged softmaxes: col (write Sc) + row (write Sr) ----------------
__global__ void k_smax(const float* __restrict__ S, float* __restrict__ Sr,
                       float* __restrict__ Sc, const float* __restrict__ cmask,
                       const float* __restrict__ qmask) {
  int blk = blockIdx.x;
  int tid = threadIdx.x;
  if (blk < BB * MM) {
    int b = blk / MM;
    int mcol = blk % MM;
    float vals[7];
    float mx = -1e30f;
    #pragma unroll
    for (int c = 0; c < 7; ++c) {
      int n = tid + c * 64;
      float s = -1e30f;
      if (n < NN)
        s = S[((size_t)b * NN + n) * MM + mcol] - 1e30f * (1.0f - cmask[b * NN + n]);
      vals[c] = s;
      mx = fmaxf(mx, s);
    }
    #pragma unroll
    for (int off = 1; off < 64; off <<= 1) mx = fmaxf(mx, __shfl_xor(mx, off));
    float sum = 0.f;
    #pragma unroll
    for (int c = 0; c < 7; ++c) { vals[c] = __expf(vals[c] - mx); sum += vals[c]; }
    #pragma unroll
    for (int off = 1; off < 64; off <<= 1) sum += __shfl_xor(sum, off);
    float inv = 1.0f / sum;
    #pragma unroll
    for (int c = 0; c < 7; ++c) {
      int n = tid + c * 64;
      if (n < NN) Sc[((size_t)b * NN + n) * MM + mcol] = vals[c] * inv;
    }
  } else {
    int bn = blk - BB * MM;
    int b = bn / NN;
    float s = -1e30f;
    if (tid < MM)
      s = S[(size_t)bn * MM + tid] - 1e30f * (1.0f - qmask[b * MM + tid]);
    float mx = s;
    #pragma unroll
    for (int off = 1; off < 64; off <<= 1) mx = fmaxf(mx, __shfl_xor(mx, off));
    float e = (tid < MM) ? __expf(s - mx) : 0.f;
    float sum = e;
    #pragma unroll
    for (int off = 1; off < 64; off <<= 1) sum += __shfl_xor(sum, off);
    if (tid < MM) Sr[(size_t)bn * MM + tid] = e / sum;
  }
}

// ---------------- U[b,m,d] = sum_k Sc[b,k,m]*C2[b,k,d]; float4 over d ----------------
__global__ void k_U(const float* __restrict__ Sc, const float* __restrict__ C2,
                    float* __restrict__ U) {
  int idx = blockIdx.x * 256 + threadIdx.x;  // BB*MM*32
  if (idx >= BB * MM * 32) return;
  int d4 = idx & 31;
  int rest = idx >> 5;
  int mcol = rest % MM;
  int b = rest / MM;
  const float* psc = Sc + (size_t)b * NN * MM + mcol;
  const float4* pc2 = (const float4*)(C2 + (size_t)b * NN * DD) + d4;
  float4 acc = {0.f, 0.f, 0.f, 0.f};
  #pragma unroll 4
  for (int kk = 0; kk < NN; ++kk) {
    float s = psc[(size_t)kk * MM];
    float4 c = pc2[(size_t)kk * 32];
    acc.x += s * c.x; acc.y += s * c.y; acc.z += s * c.z; acc.w += s * c.w;
  }
  ((float4*)U)[idx] = acc;
}

// ---------------- A, Bt = Sr @ {Q2, U}; float4 over d ----------------
__global__ void k_ABt(const float* __restrict__ Sr, const float* __restrict__ Q2,
                      const float* __restrict__ Uu, float* __restrict__ A,
                      float* __restrict__ Bt) {
  int idx = blockIdx.x * 256 + threadIdx.x;  // BB*NN*32
  if (idx >= BB * NN * 32) return;
  int d4 = idx & 31;
  int rest = idx >> 5;
  int n = rest % NN;
  int b = rest / NN;
  const float* ps = Sr + ((size_t)b * NN + n) * MM;
  const float4* pq = (const float4*)(Q2 + (size_t)b * MM * DD) + d4;
  const float4* pu = (const float4*)(Uu + (size_t)b * MM * DD) + d4;
  float4 a = {0.f, 0.f, 0.f, 0.f}, bt = {0.f, 0.f, 0.f, 0.f};
  #pragma unroll 5
  for (int mcol = 0; mcol < MM; ++mcol) {
    float s = ps[mcol];
    float4 q = pq[(size_t)mcol * 32];
    float4 u = pu[(size_t)mcol * 32];
    a.x += s * q.x; a.y += s * q.y; a.z += s * q.z; a.w += s * q.w;
    bt.x += s * u.x; bt.y += s * u.y; bt.z += s * u.z; bt.w += s * u.w;
  }
  ((float4*)A)[idx] = a;
  ((float4*)Bt)[idx] = bt;
}

// ---------------- final concat [C2, A, C2*A, C2*Bt]; float4 ----------------
__global__ void k_final(const float* __restrict__ C2, const float* __restrict__ A,
                        const float* __restrict__ Bt, float* __restrict__ out) {
  int idx = blockIdx.x * 256 + threadIdx.x;  // BB*NN*32
  if (idx >= BB * NN * 32) return;
  int d4 = idx & 31;
  int bn = idx >> 5;
  float4 c = ((const float4*)C2)[idx];
  float4 a = ((const float4*)A)[idx];
  float4 bt = ((const float4*)Bt)[idx];
  float4* po = (float4*)(out + (size_t)bn * 512);
  po[d4] = c;
  po[32 + d4] = a;
  float4 ca = {c.x * a.x, c.y * a.y, c.z * a.z, c.w * a.w};
  po[64 + d4] = ca;
  float4 cb = {c.x * bt.x, c.y * bt.y, c.z * bt.z, c.w * bt.w};
  po[96 + d4] = cb;
}

extern "C" void kernel_launch(void* const* d_in, const int* in_sizes, int n_in,
                              void* d_out, int out_size, void* d_ws, size_t ws_size,
                              hipStream_t stream) {
  (void)in_sizes; (void)n_in; (void)out_size; (void)ws_size;
  const float* ctx   = (const float*)d_in[0];
  const float* que   = (const float*)d_in[1];
  const float* cmask = (const float*)d_in[2];
  const float* qmask = (const float*)d_in[3];
  const float* ln_g  = (const float*)d_in[4];
  const float* ln_b  = (const float*)d_in[5];
  const float* dw_w  = (const float*)d_in[6];
  const float* dw_b  = (const float*)d_in[7];
  const float* pw_w  = (const float*)d_in[8];
  const float* pw_b  = (const float*)d_in[9];
  const float* Wq    = (const float*)d_in[10];
  const float* bq    = (const float*)d_in[11];
  const float* Wk    = (const float*)d_in[12];
  const float* bk    = (const float*)d_in[13];
  const float* Wv    = (const float*)d_in[14];
  const float* bv    = (const float*)d_in[15];
  const float* Wo    = (const float*)d_in[16];
  const float* bo    = (const float*)d_in[17];
  const float* Wfc   = (const float*)d_in[18];
  const float* bfc   = (const float*)d_in[19];
  const float* cq_wc = (const float*)d_in[20];
  const float* cq_wq = (const float*)d_in[21];
  const float* cq_wm = (const float*)d_in[22];
  const float* cq_b  = (const float*)d_in[23];
  float* out = (float*)d_out;
  float* ws = (float*)d_ws;

  float* Cb   = ws;
  float* Qb   = Cb + SZ_C;
  float* t1C  = Qb + SZ_Q;
  float* t1Q  = t1C + SZ_C;
  float* t2C  = t1Q + SZ_Q;
  float* t2Q  = t2C + SZ_C;
  float* t3C  = t2Q + SZ_Q;
  float* t3Q  = t3C + SZ_C;
  float* t4C  = t3Q + SZ_Q;
  float* t4Q  = t4C + SZ_C;
  float* muB  = t4Q + SZ_Q;
  float* invB = muB + SSTAT;
  float* Wcan = invB + SSTAT;
  // Wcan: 9*16384 floats; total ws usage ~74.5 MB

  int totAll = SZ_C + SZ_Q;
  int nbAll = (totAll + 255) / 256;

  k_transposeW<<<(9 * 16384 + 255) / 256, 256, 0, stream>>>(pw_w, Wo, Wfc, Wq, Wk, Wv, Wcan);
  k_pe<<<nbAll, 256, 0, stream>>>(ctx, que, Cb, Qb);

  for (int i = 0; i < NC; ++i) {
    k_lnstats<<<512, 256, 0, stream>>>(Cb, Qb, muB, invB);
    k_dw<<<nbAll, 256, 0, stream>>>(Cb, Qb, t1C, t1Q,
                                    dw_w + (size_t)i * DD * KW, dw_b + (size_t)i * DD,
                                    muB, invB, ln_g, ln_b);
    k_gemm128<0, 2><<<320, 256, 0, stream>>>(t1C, t1Q, Cb, Qb,
                                             Wcan + (size_t)i * 16384, pw_b + (size_t)i * DD,
                                             muB, invB, ln_g, ln_b);
  }
  // self-attention
  k_lnstats<<<512, 256, 0, stream>>>(Cb, Qb, muB, invB);
  k_gemm_qkv<<<960, 256, 0, stream>>>(Cb, Qb, t1C, t1Q, t2C, t2Q, t3C, t3Q,
                                      Wcan, bq, bk, bv, muB, invB, ln_g, ln_b);
  k_attn2<<<1536, 256, 0, stream>>>(t1C, t2C, t3C, t1Q, t2Q, t3Q, cmask, qmask, t4C, t4Q);
  k_gemm128<0, 1><<<320, 256, 0, stream>>>(t4C, t4Q, Cb, Qb, Wcan + 4 * 16384, bo,
                                           muB, invB, ln_g, ln_b);
  // FFN (in-place residual: each block reads its full x-region before writing)
  k_lnstats<<<512, 256, 0, stream>>>(Cb, Qb, muB, invB);
  k_gemm128<1, 1><<<320, 256, 0, stream>>>(Cb, Qb, Cb, Qb, Wcan + 5 * 16384, bfc,
                                           muB, invB, ln_g, ln_b);

  // ---- context-query attention ----
  float* C2  = t1C;
  float* Q2  = t1Q;
  float* S   = t2C;
  float* Sr  = t2C + 1638400;  // S is BB*NN*MM = 1,280,000 floats; region is SZ_C
  float* Scb = t3C;
  float* Uu  = t2Q;
  float* cd  = t3Q;
  float* qd  = t4Q;
  float* A   = t4C;
  float* Bt  = Cb;  // Cb free after k_prep has read it

  k_prep<<<3953, 256, 0, stream>>>(Cb, Qb, C2, Q2, cq_wc, cq_wq, cd, qd);
  k_S<<<(BB * NN * MM + 255) / 256, 256, 0, stream>>>(C2, Q2, cd, qd, cq_wm, cq_b, S);
  k_smax<<<BB * MM + BB * NN, 64, 0, stream>>>(S, Sr, Scb, cmask, qmask);
  k_U<<<(BB * MM * 32 + 255) / 256, 256, 0, stream>>>(Scb, C2, Uu);
  k_ABt<<<(BB * NN * 32 + 255) / 256, 256, 0, stream>>>(Sr, Q2, Uu, A, Bt);
  k_final<<<(BB * NN * 32 + 255) / 256, 256, 0, stream>>>(C2, A, Bt, out);
}

// Round 3
// 922.807 us; speedup vs baseline: 1.2217x; 1.0908x over previous
//
#include <hip/hip_runtime.h>
#include <math.h>

#define BB 64
#define DD 128
#define NN 400
#define MM 50
#define HH 8
#define KDIM 16
#define NC 4
#define KW 7

#define SZ_C (BB * DD * NN)   // 3,276,800
#define SZ_Q (BB * DD * MM)   //   409,600
#define SSTAT (BB * NN + BB * MM)  // 28,800; q stats at offset BB*NN

// ---------------- canonical weight transpose: Wcan[m][d][e] ----------------
// m 0..3: pw_w (e-major), m 4: Wo (d-major, copy), m 5: Wfc (e-major),
// m 6..8: Wq/Wk/Wv ([h][d][kd], e = h*16+kd)
__global__ void k_transposeW(const float* __restrict__ pw_w, const float* __restrict__ Wo,
                             const float* __restrict__ Wfc, const float* __restrict__ Wq,
                             const float* __restrict__ Wk, const float* __restrict__ Wv,
                             float* __restrict__ Wcan) {
  int idx = blockIdx.x * 256 + threadIdx.x;
  if (idx >= 9 * 16384) return;
  int m = idx >> 14;
  int r = idx & 16383;
  int d = r >> 7, e = r & 127;
  float v;
  if (m < 4) v = pw_w[m * 16384 + e * 128 + d];
  else if (m == 4) v = Wo[d * 128 + e];
  else if (m == 5) v = Wfc[e * 128 + d];
  else {
    const float* W = (m == 6) ? Wq : (m == 7) ? Wk : Wv;
    v = W[((e >> 4) * 128 + d) * 16 + (e & 15)];
  }
  Wcan[idx] = v;
}

// ---------------- position encoding add (both phases) ----------------
__global__ void k_pe(const float* __restrict__ xC, const float* __restrict__ xQ,
                     float* __restrict__ yC, float* __restrict__ yQ) {
  int idx = blockIdx.x * 256 + threadIdx.x;
  const float* x; float* y; int L, id2;
  if (idx < SZ_C) { x = xC; y = yC; L = NN; id2 = idx; }
  else if (idx < SZ_C + SZ_Q) { x = xQ; y = yQ; L = MM; id2 = idx - SZ_C; }
  else return;
  int l = id2 % L;
  int d = (id2 / L) % DD;
  int de = d & ~1;
  float freq = __expf((float)de * (-9.210340371976184f / 128.0f));
  float phase = (d & 1) ? 1.5707963267948966f : 0.0f;
  y[id2] = x[id2] + sinf((float)l * freq + phase);
}

// ---------------- LN stats: mu and 1/(sd+eps), ddof=1 (only after PE) ----------------
__global__ void k_lnstats(const float* __restrict__ xC, const float* __restrict__ xQ,
                          float* __restrict__ mu, float* __restrict__ inv) {
  int blk = blockIdx.x;
  const float* x; int L, lt, b, soff;
  if (blk < 448) { b = blk / 7; lt = blk % 7; x = xC; L = NN; soff = 0; }
  else { b = blk - 448; lt = 0; x = xQ; L = MM; soff = BB * NN; }
  int ll = threadIdx.x & 63;
  int dq = threadIdx.x >> 6;
  int l = lt * 64 + ll;
  __shared__ float s_sum[4][64], s_sq[4][64];
  float sum = 0.f, sq = 0.f;
  const float* px = x + (size_t)b * DD * L + l;
  if (l < L) {
    for (int d = dq * 32; d < dq * 32 + 32; ++d) {
      float v = px[(size_t)d * L];
      sum += v; sq += v * v;
    }
  }
  s_sum[dq][ll] = sum; s_sq[dq][ll] = sq;
  __syncthreads();
  if (dq == 0 && l < L) {
    float ts = s_sum[0][ll] + s_sum[1][ll] + s_sum[2][ll] + s_sum[3][ll];
    float tq = s_sq[0][ll] + s_sq[1][ll] + s_sq[2][ll] + s_sq[3][ll];
    float m = ts * (1.0f / 128.0f);
    float var = (tq - 128.0f * m * m) * (1.0f / 127.0f);
    float sd = sqrtf(fmaxf(var, 0.f));
    mu[soff + b * L + l] = m;
    inv[soff + b * L + l] = 1.0f / (sd + 1e-6f);
  }
}

// ---------------- fused conv layer ----------------
// One kernel per layer: LN (stats in via muI/invI) + depthwise conv K=7 during
// X staging + 128x128 pointwise GEMM + relu + residual + LN-stats epilogue for
// the NEXT layer (written to muO/invO, ping-pong vs muI to avoid races).
__global__ __launch_bounds__(256) void k_convgemm(
    const float* __restrict__ xC, const float* __restrict__ xQ,   // layer input (residual source)
    float* __restrict__ outC, float* __restrict__ outQ,           // layer output (different buffer!)
    const float* __restrict__ Wc,   // pointwise weights canonical [d][e]
    const float* __restrict__ pwb,  // pointwise bias [e]
    const float* __restrict__ dww,  // depthwise weights [d][7]
    const float* __restrict__ dwb,  // depthwise bias [d]
    const float* __restrict__ muI, const float* __restrict__ invI,
    float* __restrict__ muO, float* __restrict__ invO,
    const float* __restrict__ g, const float* __restrict__ beta) {
  int blk = blockIdx.x;
  int b = blk / 5, tile = blk % 5;
  const float* x; float* out; int L, l0, soff;
  if (tile < 4) { x = xC; out = outC; L = NN; l0 = tile * 128; soff = 0; }
  else { x = xQ; out = outQ; L = MM; l0 = 0; soff = BB * NN; }
  __shared__ float Wl[32 * 128];
  __shared__ float Xl[32 * 128];
  __shared__ float Sm[134], Si[134];  // LN stats halo [l0-3, l0+131)
  int tid = threadIdx.x;
  const float* xb = x + (size_t)b * DD * L;
  // stage stats halo
  for (int t = tid; t < 134; t += 256) {
    int gl = l0 + t - 3;
    bool ok = (gl >= 0 && gl < L);
    Sm[t] = ok ? muI[soff + b * L + gl] : 0.f;
    Si[t] = ok ? invI[soff + b * L + gl] : 0.f;
  }
  float acc[8][8];
  #pragma unroll
  for (int i = 0; i < 8; ++i)
    #pragma unroll
    for (int j = 0; j < 8; ++j) acc[i][j] = 0.f;
  __syncthreads();
  for (int kc = 0; kc < 4; ++kc) {
    int d0 = kc * 32;
    #pragma unroll
    for (int i = 0; i < 16; ++i) {
      int idx = i * 256 + tid;
      Wl[idx] = Wc[(size_t)(d0 + (idx >> 7)) * 128 + (idx & 127)];
    }
    // X staging with fused LN + depthwise conv.
    // Round r: thread handles row k = r*8 + tid>>5, cols c0..c0+3 (c0=(tid&31)*4).
    // Wave writes 1KB of consecutive LDS per ds_write round -> conflict-free.
    #pragma unroll
    for (int r = 0; r < 4; ++r) {
      int k = r * 8 + (tid >> 5);
      int d = d0 + k;
      int c0 = (tid & 31) * 4;
      const float* xrow = xb + (size_t)d * L;
      float gd = g[d], bd = beta[d];
      float wv[7];
      #pragma unroll
      for (int u = 0; u < 7; ++u) wv[u] = dww[d * 7 + u];
      float dbv = dwb[d];
      float xw[10];
      int gbase = l0 + c0 - 3;  // xw[s] is LN'd x at gl = gbase + s
      // fast path: aligned float4 loads covering [gbase-1, gbase+11)
      if (gbase >= 1 && gbase + 11 <= L && (((unsigned)(d * L + gbase - 1)) & 3u) == 0u) {
        const float4* p = (const float4*)&xrow[gbase - 1];
        float4 A = p[0], Bv = p[1], Cv = p[2];
        float xr[12] = {A.x, A.y, A.z, A.w, Bv.x, Bv.y, Bv.z, Bv.w, Cv.x, Cv.y, Cv.z, Cv.w};
        #pragma unroll
        for (int s = 0; s < 10; ++s)
          xw[s] = gd * (xr[s + 1] - Sm[c0 + s]) * Si[c0 + s] + bd;
      } else {
        #pragma unroll
        for (int s = 0; s < 10; ++s) {
          int gl = gbase + s;
          float v = 0.f;  // zero-pad AFTER LN (conv pads post-LN)
          if (gl >= 0 && gl < L)
            v = gd * (xrow[gl] - Sm[c0 + s]) * Si[c0 + s] + bd;
          xw[s] = v;
        }
      }
      float4 o;
      o.x = dbv; o.y = dbv; o.z = dbv; o.w = dbv;
      #pragma unroll
      for (int u = 0; u < 7; ++u) {
        o.x += wv[u] * xw[u];
        o.y += wv[u] * xw[u + 1];
        o.z += wv[u] * xw[u + 2];
        o.w += wv[u] * xw[u + 3];
      }
      *(float4*)&Xl[k * 128 + c0] = o;
    }
    __syncthreads();
    int e0 = (tid >> 4) * 8, lq = (tid & 15) * 8;
    for (int k = 0; k < 32; ++k) {
      const float4* wp = (const float4*)&Wl[k * 128 + e0];
      const float4* xp = (const float4*)&Xl[k * 128 + lq];
      float4 w0 = wp[0], w1 = wp[1], x0 = xp[0], x1 = xp[1];
      float we[8] = {w0.x, w0.y, w0.z, w0.w, w1.x, w1.y, w1.z, w1.w};
      float xe[8] = {x0.x, x0.y, x0.z, x0.w, x1.x, x1.y, x1.z, x1.w};
      #pragma unroll
      for (int i = 0; i < 8; ++i)
        #pragma unroll
        for (int j = 0; j < 8; ++j) acc[i][j] += we[i] * xe[j];
    }
    __syncthreads();
  }
  // epilogue: relu + residual (from INPUT buffer) + per-column stats
  int e0 = (tid >> 4) * 8;
  int lcb = (tid & 15) * 8;           // local col base
  int lq = l0 + lcb;
  float ssum[8], ssq[8];
  #pragma unroll
  for (int j = 0; j < 8; ++j) { ssum[j] = 0.f; ssq[j] = 0.f; }
  #pragma unroll
  for (int i = 0; i < 8; ++i) {
    float bi = pwb[e0 + i];
    float* po = out + ((size_t)b * DD + e0 + i) * L;
    const float* pr = xb + (size_t)(e0 + i) * L;
    #pragma unroll
    for (int j = 0; j < 8; ++j) {
      int l = lq + j;
      if (l < L) {
        float v = fmaxf(acc[i][j] + bi, 0.f) + pr[l];
        po[l] = v;
        ssum[j] += v; ssq[j] += v * v;
      }
    }
  }
  // stats reduce: reuse Xl (sums) / Wl (squares) as [16 groups][128 cols]
  int grp = tid >> 4;
  #pragma unroll
  for (int j = 0; j < 8; ++j) {
    Xl[grp * 128 + lcb + j] = ssum[j];
    Wl[grp * 128 + lcb + j] = ssq[j];
  }
  __syncthreads();
  if (tid < 128) {
    int l = l0 + tid;
    if (l < L) {
      float ts = 0.f, tq = 0.f;
      #pragma unroll
      for (int gg = 0; gg < 16; ++gg) { ts += Xl[gg * 128 + tid]; tq += Wl[gg * 128 + tid]; }
      float m = ts * (1.0f / 128.0f);
      float var = (tq - 128.0f * m * m) * (1.0f / 127.0f);
      float sd = sqrtf(fmaxf(var, 0.f));
      muO[soff + b * L + l] = m;
      invO[soff + b * L + l] = 1.0f / (sd + 1e-6f);
    }
  }
}

// ---------------- 128x128 GEMM over [B,128,L], both phases ----------------
// LNF: apply LN during X staging. ACT: 0=write, 1=+residual(out), 2=relu+residual.
// STATS: epilogue computes per-column LN stats of the final value -> muO/invO.
template <int LNF, int ACT, int STATS>
__global__ __launch_bounds__(256) void k_gemm128(
    const float* __restrict__ xC, const float* __restrict__ xQ,
    float* __restrict__ outC, float* __restrict__ outQ,
    const float* __restrict__ Wc, const float* __restrict__ bias,
    const float* __restrict__ mu, const float* __restrict__ inv,
    float* __restrict__ muO, float* __restrict__ invO,
    const float* __restrict__ g, const float* __restrict__ beta) {
  int blk = blockIdx.x;
  int b = blk / 5, tile = blk % 5;
  const float* x; float* out; int L, l0, soff;
  if (tile < 4) { x = xC; out = outC; L = NN; l0 = tile * 128; soff = 0; }
  else { x = xQ; out = outQ; L = MM; l0 = 0; soff = BB * NN; }
  __shared__ float Wl[32 * 128];
  __shared__ float Xl[32 * 128];
  int tid = threadIdx.x;
  float acc[8][8];
  #pragma unroll
  for (int i = 0; i < 8; ++i)
    #pragma unroll
    for (int j = 0; j < 8; ++j) acc[i][j] = 0.f;
  const float* xb = x + (size_t)b * DD * L;
  const float* pmu = mu + soff + b * L;
  const float* pin = inv + soff + b * L;
  for (int kc = 0; kc < 4; ++kc) {
    int d0 = kc * 32;
    #pragma unroll
    for (int i = 0; i < 16; ++i) {
      int idx = i * 256 + tid;
      Wl[idx] = Wc[(size_t)(d0 + (idx >> 7)) * 128 + (idx & 127)];
    }
    #pragma unroll
    for (int i = 0; i < 16; ++i) {
      int idx = i * 256 + tid;
      int k = idx >> 7, l = idx & 127;
      float v = 0.f;
      if (l0 + l < L) {
        v = xb[(size_t)(d0 + k) * L + l0 + l];
        if (LNF) v = g[d0 + k] * (v - pmu[l0 + l]) * pin[l0 + l] + beta[d0 + k];
      }
      Xl[idx] = v;
    }
    __syncthreads();
    int e0 = (tid >> 4) * 8, lq = (tid & 15) * 8;
    for (int k = 0; k < 32; ++k) {
      const float4* wp = (const float4*)&Wl[k * 128 + e0];
      const float4* xp = (const float4*)&Xl[k * 128 + lq];
      float4 w0 = wp[0], w1 = wp[1], x0 = xp[0], x1 = xp[1];
      float we[8] = {w0.x, w0.y, w0.z, w0.w, w1.x, w1.y, w1.z, w1.w};
      float xe[8] = {x0.x, x0.y, x0.z, x0.w, x1.x, x1.y, x1.z, x1.w};
      #pragma unroll
      for (int i = 0; i < 8; ++i)
        #pragma unroll
        for (int j = 0; j < 8; ++j) acc[i][j] += we[i] * xe[j];
    }
    __syncthreads();
  }
  int e0 = (tid >> 4) * 8;
  int lcb = (tid & 15) * 8;
  int lq = l0 + lcb;
  float ssum[8], ssq[8];
  #pragma unroll
  for (int j = 0; j < 8; ++j) { ssum[j] = 0.f; ssq[j] = 0.f; }
  #pragma unroll
  for (int i = 0; i < 8; ++i) {
    float bi = bias[e0 + i];
    float* po = out + ((size_t)b * DD + e0 + i) * L;
    #pragma unroll
    for (int j = 0; j < 8; ++j) {
      int l = lq + j;
      if (l < L) {
        float v = acc[i][j] + bi;
        if (ACT == 2) v = fmaxf(v, 0.f);
        if (ACT != 0) v += po[l];
        po[l] = v;
        if (STATS) { ssum[j] += v; ssq[j] += v * v; }
      }
    }
  }
  if (STATS) {
    int grp = tid >> 4;
    #pragma unroll
    for (int j = 0; j < 8; ++j) {
      Xl[grp * 128 + lcb + j] = ssum[j];
      Wl[grp * 128 + lcb + j] = ssq[j];
    }
    __syncthreads();
    if (tid < 128) {
      int l = l0 + tid;
      if (l < L) {
        float ts = 0.f, tq = 0.f;
        #pragma unroll
        for (int gg = 0; gg < 16; ++gg) { ts += Xl[gg * 128 + tid]; tq += Wl[gg * 128 + tid]; }
        float m = ts * (1.0f / 128.0f);
        float var = (tq - 128.0f * m * m) * (1.0f / 127.0f);
        float sd = sqrtf(fmaxf(var, 0.f));
        muO[soff + b * L + l] = m;
        invO[soff + b * L + l] = 1.0f / (sd + 1e-6f);
      }
    }
  }
}

// ---------------- fused QKV GEMM: 3 weight sets in one launch ----------------
__global__ __launch_bounds__(256) void k_gemm_qkv(
    const float* __restrict__ xC, const float* __restrict__ xQ,
    float* __restrict__ o1C, float* __restrict__ o1Q,
    float* __restrict__ o2C, float* __restrict__ o2Q,
    float* __restrict__ o3C, float* __restrict__ o3Q,
    const float* __restrict__ Wcan,
    const float* __restrict__ bq, const float* __restrict__ bk, const float* __restrict__ bv,
    const float* __restrict__ mu, const float* __restrict__ inv,
    const float* __restrict__ g, const float* __restrict__ beta) {
  int blk0 = blockIdx.x;
  int grp = blk0 / 320;
  int blk = blk0 - grp * 320;
  const float* Wc = Wcan + (size_t)(6 + grp) * 16384;
  const float* bias = (grp == 0) ? bq : (grp == 1) ? bk : bv;
  float* oC = (grp == 0) ? o1C : (grp == 1) ? o2C : o3C;
  float* oQ = (grp == 0) ? o1Q : (grp == 1) ? o2Q : o3Q;
  int b = blk / 5, tile = blk % 5;
  const float* x; float* out; int L, l0, soff;
  if (tile < 4) { x = xC; out = oC; L = NN; l0 = tile * 128; soff = 0; }
  else { x = xQ; out = oQ; L = MM; l0 = 0; soff = BB * NN; }
  __shared__ float Wl[32 * 128];
  __shared__ float Xl[32 * 128];
  int tid = threadIdx.x;
  float acc[8][8];
  #pragma unroll
  for (int i = 0; i < 8; ++i)
    #pragma unroll
    for (int j = 0; j < 8; ++j) acc[i][j] = 0.f;
  const float* xb = x + (size_t)b * DD * L;
  const float* pmu = mu + soff + b * L;
  const float* pin = inv + soff + b * L;
  for (int kc = 0; kc < 4; ++kc) {
    int d0 = kc * 32;
    #pragma unroll
    for (int i = 0; i < 16; ++i) {
      int idx = i * 256 + tid;
      Wl[idx] = Wc[(size_t)(d0 + (idx >> 7)) * 128 + (idx & 127)];
    }
    #pragma unroll
    for (int i = 0; i < 16; ++i) {
      int idx = i * 256 + tid;
      int k = idx >> 7, l = idx & 127;
      float v = 0.f;
      if (l0 + l < L) {
        v = xb[(size_t)(d0 + k) * L + l0 + l];
        v = g[d0 + k] * (v - pmu[l0 + l]) * pin[l0 + l] + beta[d0 + k];
      }
      Xl[idx] = v;
    }
    __syncthreads();
    int e0 = (tid >> 4) * 8, lq = (tid & 15) * 8;
    for (int k = 0; k < 32; ++k) {
      const float4* wp = (const float4*)&Wl[k * 128 + e0];
      const float4* xp = (const float4*)&Xl[k * 128 + lq];
      float4 w0 = wp[0], w1 = wp[1], x0 = xp[0], x1 = xp[1];
      float we[8] = {w0.x, w0.y, w0.z, w0.w, w1.x, w1.y, w1.z, w1.w};
      float xe[8] = {x0.x, x0.y, x0.z, x0.w, x1.x, x1.y, x1.z, x1.w};
      #pragma unroll
      for (int i = 0; i < 8; ++i)
        #pragma unroll
        for (int j = 0; j < 8; ++j) acc[i][j] += we[i] * xe[j];
    }
    __syncthreads();
  }
  int e0 = (tid >> 4) * 8, lq = l0 + (tid & 15) * 8;
  #pragma unroll
  for (int i = 0; i < 8; ++i) {
    float bi = bias[e0 + i];
    float* po = out + ((size_t)b * DD + e0 + i) * L;
    #pragma unroll
    for (int j = 0; j < 8; ++j) {
      int l = lq + j;
      if (l < L) po[l] = acc[i][j] + bi;
    }
  }
}

// ---------------- attention ----------------
// ctx: 2 blocks per (b,h) splitting the 400 queries [0,256)/[256,400);
// 1 query per thread, inactive threads exit right after staging.
__global__ __launch_bounds__(256) void k_attn2(
    const float* __restrict__ qC, const float* __restrict__ kC, const float* __restrict__ vC,
    const float* __restrict__ qQ, const float* __restrict__ kQ, const float* __restrict__ vQ,
    const float* __restrict__ cmask, const float* __restrict__ qmask,
    float* __restrict__ oC, float* __restrict__ oQ) {
  int blk = blockIdx.x;
  const float *qp, *kp, *vp, *mk; float* op; int L, b, h, q0, qcnt;
  if (blk < 1024) {
    b = blk >> 4; h = (blk >> 1) & 7; int half = blk & 1;
    qp = qC; kp = kC; vp = vC; mk = cmask; op = oC; L = NN;
    q0 = half * 256; qcnt = half ? (NN - 256) : 256;
  } else {
    int bb = blk - 1024; b = bb >> 3; h = bb & 7;
    qp = qQ; kp = kQ; vp = vQ; mk = qmask; op = oQ; L = MM;
    q0 = 0; qcnt = MM;
  }
  __shared__ float Kl[NN * KDIM];
  __shared__ float Vl[NN * KDIM];
  __shared__ float Ml[NN];
  int tid = threadIdx.x;
  size_t base = ((size_t)b * DD + h * KDIM) * L;
  int KP = (L + 7) & ~7;
  for (int idx = tid; idx < KDIM * L; idx += 256) {
    int t = idx / L, j = idx - t * L;
    Kl[j * KDIM + t] = kp[base + (size_t)t * L + j];
    Vl[j * KDIM + t] = vp[base + (size_t)t * L + j];
  }
  for (int idx = tid; idx < (KP - L) * KDIM; idx += 256) {
    int j = L + (idx >> 4), t = idx & 15;
    Kl[j * KDIM + t] = 0.f; Vl[j * KDIM + t] = 0.f;
  }
  for (int j = tid; j < KP; j += 256)
    Ml[j] = (j < L) ? -1e30f * (1.0f - mk[b * L + j]) : -1e30f;
  __syncthreads();
  if (tid >= qcnt) return;

  int i = q0 + tid;
  float q[KDIM];
  #pragma unroll
  for (int t = 0; t < KDIM; ++t) q[t] = qp[base + (size_t)t * L + i] * 0.25f;
  float m = -1e30f, ls = 0.f;
  float acc[KDIM];
  #pragma unroll
  for (int t = 0; t < KDIM; ++t) acc[t] = 0.f;
  for (int j0 = 0; j0 < KP; j0 += 8) {
    const float4* mp = (const float4*)&Ml[j0];
    float4 ma0 = mp[0], ma1 = mp[1];
    float mav[8] = {ma0.x, ma0.y, ma0.z, ma0.w, ma1.x, ma1.y, ma1.z, ma1.w};
    float s[8];
    #pragma unroll
    for (int jj = 0; jj < 8; ++jj) {
      const float4* kf = (const float4*)&Kl[(j0 + jj) * KDIM];
      float4 k0 = kf[0], k1 = kf[1], k2 = kf[2], k3 = kf[3];
      float da = q[0] * k0.x + q[1] * k0.y + q[2] * k0.z + q[3] * k0.w
               + q[4] * k1.x + q[5] * k1.y + q[6] * k1.z + q[7] * k1.w;
      float db = q[8] * k2.x + q[9] * k2.y + q[10] * k2.z + q[11] * k2.w
               + q[12] * k3.x + q[13] * k3.y + q[14] * k3.z + q[15] * k3.w;
      s[jj] = da + db + mav[jj];
    }
    float cm = s[0];
    #pragma unroll
    for (int jj = 1; jj < 8; ++jj) cm = fmaxf(cm, s[jj]);
    if (cm > m) {
      float sc = __expf(m - cm);
      ls *= sc;
      #pragma unroll
      for (int t = 0; t < KDIM; ++t) acc[t] *= sc;
      m = cm;
    }
    #pragma unroll
    for (int jj = 0; jj < 8; ++jj) {
      float p = __expf(s[jj] - m);
      ls += p;
      const float4* vf = (const float4*)&Vl[(j0 + jj) * KDIM];
      float4 v0 = vf[0], v1 = vf[1], v2 = vf[2], v3 = vf[3];
      acc[0] += p * v0.x;  acc[1] += p * v0.y;  acc[2] += p * v0.z;  acc[3] += p * v0.w;
      acc[4] += p * v1.x;  acc[5] += p * v1.y;  acc[6] += p * v1.z;  acc[7] += p * v1.w;
      acc[8] += p * v2.x;  acc[9] += p * v2.y;  acc[10] += p * v2.z; acc[11] += p * v2.w;
      acc[12] += p * v3.x; acc[13] += p * v3.y; acc[14] += p * v3.z; acc[15] += p * v3.w;
    }
  }
  float invl = 1.0f / ls;
  #pragma unroll
  for (int t = 0; t < KDIM; ++t)
    op[base + (size_t)t * L + i] = acc[t] * invl;
}

// ---------------- fused prep: tiled transposes + dotD (4 jobs, 1 launch) ----------------
__global__ void k_prep(const float* __restrict__ Cb, const float* __restrict__ Qb,
                       float* __restrict__ C2, float* __restrict__ Q2,
                       const float* __restrict__ wc, const float* __restrict__ wq,
                       float* __restrict__ cd, float* __restrict__ qd) {
  int blk = blockIdx.x, tid = threadIdx.x;
  if (blk < 3840) {
    const float* X; float* Y; int L, rem;
    if (blk < 3328) { X = Cb; Y = C2; L = NN; rem = blk; }
    else { X = Qb; Y = Q2; L = MM; rem = blk - 3328; }
    int ntl = (L + 31) / 32;
    int b = rem / (4 * ntl);
    int r2 = rem % (4 * ntl);
    int d0 = (r2 / ntl) * 32;
    int l0 = (r2 % ntl) * 32;
    __shared__ float T[32][33];
    int c = tid & 31, r8 = tid >> 5;
    const float* xb = X + (size_t)b * DD * L;
    #pragma unroll
    for (int k = 0; k < 4; ++k) {
      int r = r8 + k * 8;
      int l = l0 + c;
      T[r][c] = (l < L) ? xb[(size_t)(d0 + r) * L + l] : 0.f;
    }
    __syncthreads();
    float* yb = Y + (size_t)b * L * DD;
    #pragma unroll
    for (int k = 0; k < 4; ++k) {
      int rr = r8 + k * 8;
      int l = l0 + rr;
      if (l < L) yb[(size_t)l * DD + d0 + c] = T[c][rr];
    }
  } else if (blk < 3940) {
    int idx = (blk - 3840) * 256 + tid;
    if (idx < BB * NN) {
      int l = idx % NN, b = idx / NN;
      const float* px = Cb + (size_t)b * DD * NN + l;
      float acc = 0.f;
      for (int d = 0; d < DD; ++d) acc += px[(size_t)d * NN] * wc[d];
      cd[idx] = acc;
    }
  } else {
    int idx = (blk - 3940) * 256 + tid;
    if (idx < BB * MM) {
      int l = idx % MM, b = idx / MM;
      const float* px = Qb + (size_t)b * DD * MM + l;
      float acc = 0.f;
      for (int d = 0; d < DD; ++d) acc += px[(size_t)d * MM] * wq[d];
      qd[idx] = acc;
    }
  }
}

// ---------------- S[b,n,m] trilinear (reads row-major C2/Q2, float4) ----------------
__global__ void k_S(const float* __restrict__ C2, const float* __restrict__ Q2,
                    const float* __restrict__ cd, const float* __restrict__ qd,
                    const float* __restrict__ wm, const float* __restrict__ bias,
                    float* __restrict__ S) {
  int idx = blockIdx.x * 256 + threadIdx.x;
  if (idx >= BB * NN * MM) return;
  int mcol = idx % MM;
  int n = (idx / MM) % NN;
  int b = idx / (MM * NN);
  const float4* pc = (const float4*)(C2 + ((size_t)b * NN + n) * DD);
  const float4* pq = (const float4*)(Q2 + ((size_t)b * MM + mcol) * DD);
  const float4* pw = (const float4*)wm;
  float a0 = 0.f, a1 = 0.f;
  #pragma unroll 4
  for (int d4 = 0; d4 < 32; d4 += 2) {
    float4 c0 = pc[d4], w0 = pw[d4], q0 = pq[d4];
    float4 c1 = pc[d4 + 1], w1 = pw[d4 + 1], q1 = pq[d4 + 1];
    a0 += (c0.x * w0.x) * q0.x + (c0.y * w0.y) * q0.y + (c0.z * w0.z) * q0.z + (c0.w * w0.w) * q0.w;
    a1 += (c1.x * w1.x) * q1.x + (c1.y * w1.y) * q1.y + (c1.z * w1.z) * q1.z + (c1.w * w1.w) * q1.w;
  }
  S[idx] = a0 + a1 + cd[b * NN + n] + qd[b * MM + mcol] + bias[0];
}

// ---------------- merged softmaxes: col (write Sc) + row (write Sr) ----------------
__global__ void k_smax(const float* __restrict__ S, float* __restrict__ Sr,
                       float* __restrict__ Sc, const float* __restrict__ cmask,
                       const float* __restrict__ qmask) {
  int blk = blockIdx.x;
  int tid = threadIdx.x;
  if (blk < BB * MM) {
    int b = blk / MM;
    int mcol = blk % MM;
    float vals[7];
    float mx = -1e30f;
    #pragma unroll
    for (int c = 0; c < 7; ++c) {
      int n = tid + c * 64;
      float s = -1e30f;
      if (n < NN)
        s = S[((size_t)b * NN + n) * MM + mcol] - 1e30f * (1.0f - cmask[b * NN + n]);
      vals[c] = s;
      mx = fmaxf(mx, s);
    }
    #pragma unroll
    for (int off = 1; off < 64; off <<= 1) mx = fmaxf(mx, __shfl_xor(mx, off));
    float sum = 0.f;
    #pragma unroll
    for (int c = 0; c < 7; ++c) { vals[c] = __expf(vals[c] - mx); sum += vals[c]; }
    #pragma unroll
    for (int off = 1; off < 64; off <<= 1) sum += __shfl_xor(sum, off);
    float inv = 1.0f / sum;
    #pragma unroll
    for (int c = 0; c < 7; ++c) {
      int n = tid + c * 64;
      if (n < NN) Sc[((size_t)b * NN + n) * MM + mcol] = vals[c] * inv;
    }
  } else {
    int bn = blk - BB * MM;
    int b = bn / NN;
    float s = -1e30f;
    if (tid < MM)
      s = S[(size_t)bn * MM + tid] - 1e30f * (1.0f - qmask[b * MM + tid]);
    float mx = s;
    #pragma unroll
    for (int off = 1; off < 64; off <<= 1) mx = fmaxf(mx, __shfl_xor(mx, off));
    float e = (tid < MM) ? __expf(s - mx) : 0.f;
    float sum = e;
    #pragma unroll
    for (int off = 1; off < 64; off <<= 1) sum += __shfl_xor(sum, off);
    if (tid < MM) Sr[(size_t)bn * MM + tid] = e / sum;
  }
}

// ---------------- U[b,m,d] = sum_k Sc[b,k,m]*C2[b,k,d]; float4 over d ----------------
__global__ void k_U(const float* __restrict__ Sc, const float* __restrict__ C2,
                    float* __restrict__ U) {
  int idx = blockIdx.x * 256 + threadIdx.x;
  if (idx >= BB * MM * 32) return;
  int d4 = idx & 31;
  int rest = idx >> 5;
  int mcol = rest % MM;
  int b = rest / MM;
  const float* psc = Sc + (size_t)b * NN * MM + mcol;
  const float4* pc2 = (const float4*)(C2 + (size_t)b * NN * DD) + d4;
  float4 acc = {0.f, 0.f, 0.f, 0.f};
  #pragma unroll 4
  for (int kk = 0; kk < NN; ++kk) {
    float s = psc[(size_t)kk * MM];
    float4 c = pc2[(size_t)kk * 32];
    acc.x += s * c.x; acc.y += s * c.y; acc.z += s * c.z; acc.w += s * c.w;
  }
  ((float4*)U)[idx] = acc;
}

// ---------------- A, Bt = Sr @ {Q2, U}; float4 over d ----------------
__global__ void k_ABt(const float* __restrict__ Sr, const float* __restrict__ Q2,
                      const float* __restrict__ Uu, float* __restrict__ A,
                      float* __restrict__ Bt) {
  int idx = blockIdx.x * 256 + threadIdx.x;
  if (idx >= BB * NN * 32) return;
  int d4 = idx & 31;
  int rest = idx >> 5;
  int n = rest % NN;
  int b = rest / NN;
  const float* ps = Sr + ((size_t)b * NN + n) * MM;
  const float4* pq = (const float4*)(Q2 + (size_t)b * MM * DD) + d4;
  const float4* pu = (const float4*)(Uu + (size_t)b * MM * DD) + d4;
  float4 a = {0.f, 0.f, 0.f, 0.f}, bt = {0.f, 0.f, 0.f, 0.f};
  #pragma unroll 5
  for (int mcol = 0; mcol < MM; ++mcol) {
    float s = ps[mcol];
    float4 q = pq[(size_t)mcol * 32];
    float4 u = pu[(size_t)mcol * 32];
    a.x += s * q.x; a.y += s * q.y; a.z += s * q.z; a.w += s * q.w;
    bt.x += s * u.x; bt.y += s * u.y; bt.z += s * u.z; bt.w += s * u.w;
  }
  ((float4*)A)[idx] = a;
  ((float4*)Bt)[idx] = bt;
}

// ---------------- final concat [C2, A, C2*A, C2*Bt]; float4 ----------------
__global__ void k_final(const float* __restrict__ C2, const float* __restrict__ A,
                        const float* __restrict__ Bt, float* __restrict__ out) {
  int idx = blockIdx.x * 256 + threadIdx.x;
  if (idx >= BB * NN * 32) return;
  int d4 = idx & 31;
  int bn = idx >> 5;
  float4 c = ((const float4*)C2)[idx];
  float4 a = ((const float4*)A)[idx];
  float4 bt = ((const float4*)Bt)[idx];
  float4* po = (float4*)(out + (size_t)bn * 512);
  po[d4] = c;
  po[32 + d4] = a;
  float4 ca = {c.x * a.x, c.y * a.y, c.z * a.z, c.w * a.w};
  po[64 + d4] = ca;
  float4 cb = {c.x * bt.x, c.y * bt.y, c.z * bt.z, c.w * bt.w};
  po[96 + d4] = cb;
}

extern "C" void kernel_launch(void* const* d_in, const int* in_sizes, int n_in,
                              void* d_out, int out_size, void* d_ws, size_t ws_size,
                              hipStream_t stream) {
  (void)in_sizes; (void)n_in; (void)out_size; (void)ws_size;
  const float* ctx   = (const float*)d_in[0];
  const float* que   = (const float*)d_in[1];
  const float* cmask = (const float*)d_in[2];
  const float* qmask = (const float*)d_in[3];
  const float* ln_g  = (const float*)d_in[4];
  const float* ln_b  = (const float*)d_in[5];
  const float* dw_w  = (const float*)d_in[6];
  const float* dw_b  = (const float*)d_in[7];
  const float* pw_w  = (const float*)d_in[8];
  const float* pw_b  = (const float*)d_in[9];
  const float* Wq    = (const float*)d_in[10];
  const float* bq    = (const float*)d_in[11];
  const float* Wk    = (const float*)d_in[12];
  const float* bk    = (const float*)d_in[13];
  const float* Wv    = (const float*)d_in[14];
  const float* bv    = (const float*)d_in[15];
  const float* Wo    = (const float*)d_in[16];
  const float* bo    = (const float*)d_in[17];
  const float* Wfc   = (const float*)d_in[18];
  const float* bfc   = (const float*)d_in[19];
  const float* cq_wc = (const float*)d_in[20];
  const float* cq_wq = (const float*)d_in[21];
  const float* cq_wm = (const float*)d_in[22];
  const float* cq_b  = (const float*)d_in[23];
  float* out = (float*)d_out;
  float* ws = (float*)d_ws;

  float* Cb   = ws;
  float* Qb   = Cb + SZ_C;
  float* t1C  = Qb + SZ_Q;
  float* t1Q  = t1C + SZ_C;
  float* t2C  = t1Q + SZ_Q;
  float* t2Q  = t2C + SZ_C;
  float* t3C  = t2Q + SZ_Q;
  float* t3Q  = t3C + SZ_C;
  float* t4C  = t3Q + SZ_Q;
  float* t4Q  = t4C + SZ_C;
  float* mu0  = t4Q + SZ_Q;
  float* inv0 = mu0 + SSTAT;
  float* mu1  = inv0 + SSTAT;
  float* inv1 = mu1 + SSTAT;
  float* Wcan = inv1 + SSTAT;

  int totAll = SZ_C + SZ_Q;
  int nbAll = (totAll + 255) / 256;

  k_transposeW<<<(9 * 16384 + 255) / 256, 256, 0, stream>>>(pw_w, Wo, Wfc, Wq, Wk, Wv, Wcan);
  k_pe<<<nbAll, 256, 0, stream>>>(ctx, que, Cb, Qb);
  k_lnstats<<<512, 256, 0, stream>>>(Cb, Qb, mu0, inv0);

  // conv layers: fused LN+dwconv+pwGEMM+relu+residual+stats. Ping-pong Cb <-> t1.
  for (int i = 0; i < NC; ++i) {
    const float* inC = (i & 1) ? t1C : Cb;
    const float* inQ = (i & 1) ? t1Q : Qb;
    float* oC = (i & 1) ? Cb : t1C;
    float* oQ = (i & 1) ? Qb : t1Q;
    const float* mI = (i & 1) ? mu1 : mu0;
    const float* iI = (i & 1) ? inv1 : inv0;
    float* mO = (i & 1) ? mu0 : mu1;
    float* iO = (i & 1) ? inv0 : inv1;
    k_convgemm<<<320, 256, 0, stream>>>(inC, inQ, oC, oQ,
                                        Wcan + (size_t)i * 16384, pw_b + (size_t)i * DD,
                                        dw_w + (size_t)i * DD * KW, dw_b + (size_t)i * DD,
                                        mI, iI, mO, iO, ln_g, ln_b);
  }
  // after 4 layers (even), result in Cb with stats in mu0/inv0.
  // self-attention
  k_gemm_qkv<<<960, 256, 0, stream>>>(Cb, Qb, t1C, t1Q, t2C, t2Q, t3C, t3Q,
                                      Wcan, bq, bk, bv, mu0, inv0, ln_g, ln_b);
  k_attn2<<<1536, 256, 0, stream>>>(t1C, t2C, t3C, t1Q, t2Q, t3Q, cmask, qmask, t4C, t4Q);
  // Wo projection: +residual into Cb, stats of result -> mu1/inv1
  k_gemm128<0, 1, 1><<<320, 256, 0, stream>>>(t4C, t4Q, Cb, Qb, Wcan + 4 * 16384, bo,
                                              mu0, inv0, mu1, inv1, ln_g, ln_b);
  // FFN: LN(stats mu1) + GEMM + residual, in-place on Cb
  k_gemm128<1, 1, 0><<<320, 256, 0, stream>>>(Cb, Qb, Cb, Qb, Wcan + 5 * 16384, bfc,
                                              mu1, inv1, mu0, inv0, ln_g, ln_b);

  // ---- context-query attention ----
  float* C2  = t1C;
  float* Q2  = t1Q;
  float* S   = t2C;
  float* Sr  = t2C + 1638400;
  float* Scb = t3C;
  float* Uu  = t2Q;
  float* cd  = t3Q;
  float* qd  = t4Q;
  float* A   = t4C;
  float* Bt  = Cb;

  k_prep<<<3953, 256, 0, stream>>>(Cb, Qb, C2, Q2, cq_wc, cq_wq, cd, qd);
  k_S<<<(BB * NN * MM + 255) / 256, 256, 0, stream>>>(C2, Q2, cd, qd, cq_wm, cq_b, S);
  k_smax<<<BB * MM + BB * NN, 64, 0, stream>>>(S, Sr, Scb, cmask, qmask);
  k_U<<<(BB * MM * 32 + 255) / 256, 256, 0, stream>>>(Scb, C2, Uu);
  k_ABt<<<(BB * NN * 32 + 255) / 256, 256, 0, stream>>>(Sr, Q2, Uu, A, Bt);
  k_final<<<(BB * NN * 32 + 255) / 256, 256, 0, stream>>>(C2, A, Bt, out);
}